// Round 5
// baseline (801.321 us; speedup 1.0000x reference)
//
#include <hip/hip_runtime.h>
#include <math.h>

// Problem constants
#define BGRAPH 64
#define NNODE  512
#define NTOT   32768        // BGRAPH*NNODE
#define CIN    128
#define HDIM   128
#define EDIM_  5
#define EDGES  524288
#define K1C    256
#define K2C    128

using f32x4 = __attribute__((ext_vector_type(4))) float;
using s16x8 = __attribute__((ext_vector_type(8))) short;

__device__ __forceinline__ short f2bf(float f) {
    union { float f; unsigned u; } v; v.f = f;
    unsigned r = v.u + 0x7fffu + ((v.u >> 16) & 1u);   // RNE
    return (short)(r >> 16);
}
__device__ __forceinline__ float bf2f(short s) {
    union { unsigned u; float f; } v; v.u = ((unsigned)(unsigned short)s) << 16;
    return v.f;
}

// ---------------------------------------------------------------------------
// BatchNorm statistics: 256 blocks, float4 loads, per-block partials (no atomics)
// ---------------------------------------------------------------------------
__global__ __launch_bounds__(256) void bn_stats_kernel(const float* __restrict__ x,
                                                       float* __restrict__ psum,
                                                       float* __restrict__ psq) {
    int tid = threadIdx.x, bid = blockIdx.x;
    long idx0 = (long)bid * 256 + tid;            // float4 index
    float4 s = {0.f, 0.f, 0.f, 0.f}, q = {0.f, 0.f, 0.f, 0.f};
#pragma unroll
    for (int it = 0; it < 16; ++it) {             // 256*256*16*4 = NTOT*CIN
        float4 v = *(const float4*)(x + (idx0 + (long)it * 65536) * 4);
        s.x += v.x; s.y += v.y; s.z += v.z; s.w += v.w;
        q.x += v.x * v.x; q.y += v.y * v.y; q.z += v.z * v.z; q.w += v.w * v.w;
    }
    __shared__ float ss[128], sq[128];
    if (tid < 128) { ss[tid] = 0.f; sq[tid] = 0.f; }
    __syncthreads();
    int c0 = (tid & 31) * 4;                      // fixed channels per thread
    atomicAdd(&ss[c0 + 0], s.x); atomicAdd(&ss[c0 + 1], s.y);
    atomicAdd(&ss[c0 + 2], s.z); atomicAdd(&ss[c0 + 3], s.w);
    atomicAdd(&sq[c0 + 0], q.x); atomicAdd(&sq[c0 + 1], q.y);
    atomicAdd(&sq[c0 + 2], q.z); atomicAdd(&sq[c0 + 3], q.w);
    __syncthreads();
    if (tid < 128) {
        psum[bid * 128 + tid] = ss[tid];
        psq[bid * 128 + tid]  = sq[tid];
    }
}

__global__ __launch_bounds__(128) void bn_finalize_kernel(const float* __restrict__ psum,
                                                          const float* __restrict__ psq,
                                                          const float* __restrict__ gamma,
                                                          const float* __restrict__ beta,
                                                          float* __restrict__ scale,
                                                          float* __restrict__ shift) {
    int c = threadIdx.x;
    float s = 0.f, q = 0.f;
    for (int b = 0; b < 256; ++b) { s += psum[b * 128 + c]; q += psq[b * 128 + c]; }
    float mu  = s / (float)NTOT;
    float var = q / (float)NTOT - mu * mu;
    float rstd = rsqrtf(var + 1e-5f);
    float sc = gamma[c] * rstd;
    scale[c] = sc;
    shift[c] = beta[c] - mu * sc;
}

// ---------------------------------------------------------------------------
// Pack Wq|Wk|Wv|Wskip into [128,512] and biases into [512]
// ---------------------------------------------------------------------------
__global__ __launch_bounds__(256) void pack_w4_kernel(const float* __restrict__ Wq, const float* __restrict__ Wk,
                                                      const float* __restrict__ Wv, const float* __restrict__ Ws,
                                                      const float* __restrict__ bq, const float* __restrict__ bk,
                                                      const float* __restrict__ bv, const float* __restrict__ bs,
                                                      float* __restrict__ W4, float* __restrict__ bias4) {
    int i = blockIdx.x * 256 + threadIdx.x;
    if (i < 128 * 512) {
        int k = i / 512, j = i % 512;
        float v;
        if (j < 128)      v = Wq[k * 128 + j];
        else if (j < 256) v = Wk[k * 128 + (j - 128)];
        else if (j < 384) v = Wv[k * 128 + (j - 256)];
        else              v = Ws[k * 128 + (j - 384)];
        W4[i] = v;
    }
    if (i < 512) {
        float v;
        if (i < 128)      v = bq[i];
        else if (i < 256) v = bk[i - 128];
        else if (i < 384) v = bv[i - 256];
        else              v = bs[i - 384];
        bias4[i] = v;
    }
}

// ---------------------------------------------------------------------------
// CSR build: histogram, scan, scatter
// ---------------------------------------------------------------------------
__global__ __launch_bounds__(256) void hist_kernel(const int* __restrict__ ei,
                                                   int* __restrict__ deg_src,
                                                   int* __restrict__ deg_dst) {
    int e = blockIdx.x * 256 + threadIdx.x;
    if (e < EDGES) {
        atomicAdd(&deg_src[ei[e]], 1);
        atomicAdd(&deg_dst[ei[EDGES + e]], 1);
    }
}

__global__ __launch_bounds__(1024) void scan_kernel(const int* __restrict__ deg,
                                                    int* __restrict__ rowptr,
                                                    int* __restrict__ cursor) {
    __shared__ int part[1024];
    int tid = threadIdx.x;
    int base = tid * 32;
    int s = 0;
    for (int i = 0; i < 32; ++i) s += deg[base + i];
    part[tid] = s;
    __syncthreads();
    for (int off = 1; off < 1024; off <<= 1) {
        int v = part[tid];
        int add = (tid >= off) ? part[tid - off] : 0;
        __syncthreads();
        part[tid] = v + add;
        __syncthreads();
    }
    int run = (tid == 0) ? 0 : part[tid - 1];
    for (int i = 0; i < 32; ++i) {
        rowptr[base + i] = run;
        cursor[base + i] = run;
        run += deg[base + i];
    }
}

__global__ __launch_bounds__(256) void scatter_kernel(const int* __restrict__ ei,
                                                      int* __restrict__ cur_src, int* __restrict__ cur_dst,
                                                      int* __restrict__ eid_src, int* __restrict__ eid_dst) {
    int e = blockIdx.x * 256 + threadIdx.x;
    if (e < EDGES) {
        int s = ei[e], d = ei[EDGES + e];
        eid_src[atomicAdd(&cur_src[s], 1)] = e;
        eid_dst[atomicAdd(&cur_dst[d], 1)] = e;
    }
}

// ---------------------------------------------------------------------------
// BF16 MFMA GEMM, fp32 global inputs (converted at staging).
// OBF16: epilogue stores bf16 instead of fp32.
// ---------------------------------------------------------------------------
template <bool TRANS_A, bool AFFINE, bool RELU, bool DUAL, bool OBF16>
__global__ __launch_bounds__(256) void mgemm(const float* __restrict__ A,
                                             const float* __restrict__ B,
                                             const float* __restrict__ A2,
                                             const float* __restrict__ B2,
                                             int Ksplit,
                                             const float* __restrict__ bias,
                                             void* __restrict__ Cv,
                                             const float* __restrict__ scale,
                                             const float* __restrict__ shift,
                                             int M, int Nc, int K,
                                             int lda, int ldb, int ldc,
                                             long sA, long sB, long sC) {
    __shared__ __align__(16) short As[128 * 40];
    __shared__ __align__(16) short Bs[128 * 40];
    A += (long)blockIdx.z * sA;
    B += (long)blockIdx.z * sB;
    float* C = (float*)Cv + (OBF16 ? 0 : (long)blockIdx.z * sC);
    short* Cs = (short*)Cv + (OBF16 ? (long)blockIdx.z * sC : 0);
    const int m0 = blockIdx.y * 128, n0 = blockIdx.x * 128;
    const int tid = threadIdx.x;
    const int lane16 = tid & 15;
    const int quad = (tid & 63) >> 4;
    const int wrow = (tid >> 6) >> 1, wcol = (tid >> 6) & 1;

    f32x4 acc[4][4] = {};

    for (int k0 = 0; k0 < K; k0 += 32) {
        const float* Au = A; const float* Bu = B; int ku = k0;
        if (DUAL && k0 >= Ksplit) { Au = A2; Bu = B2; ku = k0 - Ksplit; }

        if (!TRANS_A) {
#pragma unroll
            for (int p = 0; p < 4; ++p) {
                int idx = tid + p * 256;
                int row = idx >> 3, c4 = idx & 7;
                float4 v = *(const float4*)(Au + (long)(m0 + row) * lda + ku + c4 * 4);
                if (AFFINE) {
                    int k = ku + c4 * 4;
                    v.x = v.x * scale[k] + shift[k];
                    v.y = v.y * scale[k + 1] + shift[k + 1];
                    v.z = v.z * scale[k + 2] + shift[k + 2];
                    v.w = v.w * scale[k + 3] + shift[k + 3];
                }
                *(short4*)&As[row * 40 + c4 * 4] =
                    make_short4(f2bf(v.x), f2bf(v.y), f2bf(v.z), f2bf(v.w));
            }
        } else {
            int c4 = tid & 31, g = tid >> 5;
            const float* src = Au + (long)(ku + g * 4) * lda + m0 + c4 * 4;
            float4 r0 = *(const float4*)(src);
            float4 r1 = *(const float4*)(src + lda);
            float4 r2 = *(const float4*)(src + 2 * lda);
            float4 r3 = *(const float4*)(src + 3 * lda);
            short* d = &As[(c4 * 4) * 40 + g * 4];
            *(short4*)(d + 0 * 40) = make_short4(f2bf(r0.x), f2bf(r1.x), f2bf(r2.x), f2bf(r3.x));
            *(short4*)(d + 1 * 40) = make_short4(f2bf(r0.y), f2bf(r1.y), f2bf(r2.y), f2bf(r3.y));
            *(short4*)(d + 2 * 40) = make_short4(f2bf(r0.z), f2bf(r1.z), f2bf(r2.z), f2bf(r3.z));
            *(short4*)(d + 3 * 40) = make_short4(f2bf(r0.w), f2bf(r1.w), f2bf(r2.w), f2bf(r3.w));
        }
        {
            int c4 = tid & 31, g = tid >> 5;
            const float* src = Bu + (long)(ku + g * 4) * ldb + n0 + c4 * 4;
            float4 r0 = *(const float4*)(src);
            float4 r1 = *(const float4*)(src + ldb);
            float4 r2 = *(const float4*)(src + 2 * ldb);
            float4 r3 = *(const float4*)(src + 3 * ldb);
            short* d = &Bs[(c4 * 4) * 40 + g * 4];
            *(short4*)(d + 0 * 40) = make_short4(f2bf(r0.x), f2bf(r1.x), f2bf(r2.x), f2bf(r3.x));
            *(short4*)(d + 1 * 40) = make_short4(f2bf(r0.y), f2bf(r1.y), f2bf(r2.y), f2bf(r3.y));
            *(short4*)(d + 2 * 40) = make_short4(f2bf(r0.z), f2bf(r1.z), f2bf(r2.z), f2bf(r3.z));
            *(short4*)(d + 3 * 40) = make_short4(f2bf(r0.w), f2bf(r1.w), f2bf(r2.w), f2bf(r3.w));
        }
        __syncthreads();

        s16x8 af[4], bf[4];
#pragma unroll
        for (int t = 0; t < 4; ++t) {
            af[t] = *(const s16x8*)&As[(wrow * 64 + t * 16 + lane16) * 40 + quad * 8];
            bf[t] = *(const s16x8*)&Bs[(wcol * 64 + t * 16 + lane16) * 40 + quad * 8];
        }
#pragma unroll
        for (int i = 0; i < 4; ++i)
#pragma unroll
            for (int j = 0; j < 4; ++j)
                acc[i][j] = __builtin_amdgcn_mfma_f32_16x16x32_bf16(af[i], bf[j], acc[i][j], 0, 0, 0);
        __syncthreads();
    }

#pragma unroll
    for (int i = 0; i < 4; ++i) {
        int gm = m0 + wrow * 64 + i * 16 + quad * 4;
#pragma unroll
        for (int j = 0; j < 4; ++j) {
            int gn = n0 + wcol * 64 + j * 16 + lane16;
            float bv = bias ? bias[gn] : 0.f;
#pragma unroll
            for (int r = 0; r < 4; ++r) {
                float val = acc[i][j][r] + bv;
                if (RELU) val = fmaxf(val, 0.f);
                if (OBF16) Cs[(long)(gm + r) * ldc + gn] = f2bf(val);
                else       C[(long)(gm + r) * ldc + gn] = val;
            }
        }
    }
}

// ---------------------------------------------------------------------------
// BF16-input MFMA GEMM (no conversion): C = outscale * (A @ B), batched.
// ---------------------------------------------------------------------------
template <bool TRANS_B>
__global__ __launch_bounds__(256) void bgemm(const short* __restrict__ A,
                                             const short* __restrict__ B,
                                             float* __restrict__ C,
                                             float outscale,
                                             int M, int Nc, int K,
                                             int lda, int ldb, int ldc,
                                             long sA, long sB, long sC) {
    __shared__ __align__(16) short As[128 * 40];
    __shared__ __align__(16) short Bs[128 * 40];
    A += (long)blockIdx.z * sA;
    B += (long)blockIdx.z * sB;
    C += (long)blockIdx.z * sC;
    const int m0 = blockIdx.y * 128, n0 = blockIdx.x * 128;
    const int tid = threadIdx.x;
    const int lane16 = tid & 15;
    const int quad = (tid & 63) >> 4;
    const int wrow = (tid >> 6) >> 1, wcol = (tid >> 6) & 1;

    f32x4 acc[4][4] = {};

    for (int k0 = 0; k0 < K; k0 += 32) {
#pragma unroll
        for (int p = 0; p < 2; ++p) {
            int u = tid + p * 256;
            int row = u >> 2, g = u & 3;
            *(s16x8*)&As[row * 40 + g * 8] =
                *(const s16x8*)(A + (long)(m0 + row) * lda + k0 + g * 8);
        }
        if (TRANS_B) {
#pragma unroll
            for (int p = 0; p < 2; ++p) {
                int u = tid + p * 256;
                int row = u >> 2, g = u & 3;
                *(s16x8*)&Bs[row * 40 + g * 8] =
                    *(const s16x8*)(B + (long)(n0 + row) * ldb + k0 + g * 8);
            }
        } else {
            int c4 = tid & 31, g = tid >> 5;
            const short* src = B + (long)(k0 + g * 4) * ldb + n0 + c4 * 4;
            short4 r0 = *(const short4*)(src);
            short4 r1 = *(const short4*)(src + ldb);
            short4 r2 = *(const short4*)(src + 2 * ldb);
            short4 r3 = *(const short4*)(src + 3 * ldb);
            short* d = &Bs[(c4 * 4) * 40 + g * 4];
            *(short4*)(d + 0 * 40) = make_short4(r0.x, r1.x, r2.x, r3.x);
            *(short4*)(d + 1 * 40) = make_short4(r0.y, r1.y, r2.y, r3.y);
            *(short4*)(d + 2 * 40) = make_short4(r0.z, r1.z, r2.z, r3.z);
            *(short4*)(d + 3 * 40) = make_short4(r0.w, r1.w, r2.w, r3.w);
        }
        __syncthreads();

        s16x8 af[4], bf[4];
#pragma unroll
        for (int t = 0; t < 4; ++t) {
            af[t] = *(const s16x8*)&As[(wrow * 64 + t * 16 + lane16) * 40 + quad * 8];
            bf[t] = *(const s16x8*)&Bs[(wcol * 64 + t * 16 + lane16) * 40 + quad * 8];
        }
#pragma unroll
        for (int i = 0; i < 4; ++i)
#pragma unroll
            for (int j = 0; j < 4; ++j)
                acc[i][j] = __builtin_amdgcn_mfma_f32_16x16x32_bf16(af[i], bf[j], acc[i][j], 0, 0, 0);
        __syncthreads();
    }

#pragma unroll
    for (int i = 0; i < 4; ++i) {
        int gm = m0 + wrow * 64 + i * 16 + quad * 4;
#pragma unroll
        for (int j = 0; j < 4; ++j) {
            int gn = n0 + wcol * 64 + j * 16 + lane16;
#pragma unroll
            for (int r = 0; r < 4; ++r)
                C[(long)(gm + r) * ldc + gn] = acc[i][j][r] * outscale;
        }
    }
}

// ---------------------------------------------------------------------------
// qWe[node][d] = (q[node,:] . We[d,:]) / sqrt(H) — thread per (node,d)
// ---------------------------------------------------------------------------
__global__ __launch_bounds__(256) void qwe_kernel(const short* __restrict__ qkvs,
                                                  const float* __restrict__ We,
                                                  float* __restrict__ qWe) {
    __shared__ float sWe[EDIM_ * 128];
    for (int i = threadIdx.x; i < EDIM_ * 128; i += 256) sWe[i] = We[i];
    __syncthreads();
    int i = blockIdx.x * 256 + threadIdx.x;        // < NTOT*5
    int node = i / 5, d = i - node * 5;
    const s16x8* row = (const s16x8*)(qkvs + (long)node * 512);
    float acc = 0.f;
#pragma unroll
    for (int g = 0; g < 16; ++g) {
        s16x8 v = row[g];
#pragma unroll
        for (int j = 0; j < 8; ++j) acc += bf2f(v[j]) * sWe[d * 128 + g * 8 + j];
    }
    qWe[i] = acc * 0.08838834764831845f;           // 1/sqrt(128)
}

// ---------------------------------------------------------------------------
// Edge-parallel softmax accumulation (no max-pass: logits bounded ~|3|).
// w = exp(S[dst,src] + eattr.qWe[dst]); alpha[e]=w; l[dst]+=w; ea5[dst]+=w*ea.
// ---------------------------------------------------------------------------
__global__ __launch_bounds__(256) void esoftmax_edge_kernel(const float* __restrict__ S,
                                                            const int* __restrict__ ei,
                                                            const float* __restrict__ eattr,
                                                            const float* __restrict__ qWe,
                                                            float* __restrict__ alpha,
                                                            float* __restrict__ l,
                                                            float* __restrict__ ea5) {
    int e = blockIdx.x * 256 + threadIdx.x;
    int src = ei[e] & 511;
    int dst = ei[EDGES + e];
    float lg = S[(long)dst * 512 + src];
    float ea[EDIM_];
#pragma unroll
    for (int d = 0; d < EDIM_; ++d) {
        ea[d] = eattr[e * EDIM_ + d];
        lg += ea[d] * qWe[dst * EDIM_ + d];
    }
    float wv = expf(lg);
    alpha[e] = wv;
    atomicAdd(&l[dst], wv);
#pragma unroll
    for (int d = 0; d < EDIM_; ++d) atomicAdd(&ea5[dst * EDIM_ + d], wv * ea[d]);
}

__global__ __launch_bounds__(256) void invl_kernel(float* __restrict__ l) {
    int n = blockIdx.x * 256 + threadIdx.x;
    float v = l[n];
    l[n] = (v > 0.f) ? 1.f / v : 0.f;
}

// ---------------------------------------------------------------------------
// Edge-parallel P build: P[dst,src] += alpha[e]*inv_l[dst] (bf16 via CAS)
// ---------------------------------------------------------------------------
__device__ __forceinline__ void bf16_atomic_add(short* p, float val) {
    unsigned* word = (unsigned*)((size_t)p & ~(size_t)3);
    bool hi = ((size_t)p & 2) != 0;
    unsigned old = *word, assumed;
    do {
        assumed = old;
        unsigned short h = hi ? (unsigned short)(assumed >> 16) : (unsigned short)(assumed & 0xffff);
        unsigned short nh = (unsigned short)f2bf(bf2f((short)h) + val);
        unsigned newv = hi ? ((assumed & 0x0000ffffu) | ((unsigned)nh << 16))
                           : ((assumed & 0xffff0000u) | nh);
        old = atomicCAS(word, assumed, newv);
    } while (old != assumed);
}

__global__ __launch_bounds__(256) void pbuild_edge_kernel(const float* __restrict__ alpha,
                                                          const float* __restrict__ inv_l,
                                                          const int* __restrict__ ei,
                                                          short* __restrict__ P) {
    int e = blockIdx.x * 256 + threadIdx.x;
    int src = ei[e] & 511;
    int dst = ei[EDGES + e];
    bf16_atomic_add(P + (long)dst * 512 + src, alpha[e] * inv_l[dst]);
}

// ---------------------------------------------------------------------------
// h = relu(agg + inv_l * (ea5 @ We) + skip)   (in place over agg)
// ---------------------------------------------------------------------------
__global__ __launch_bounds__(256) void hassemble_kernel(float* __restrict__ h,
                                                        const float* __restrict__ ea5,
                                                        const float* __restrict__ inv_l,
                                                        const float* __restrict__ We,
                                                        const short* __restrict__ qkvs) {
    long i = (long)blockIdx.x * 256 + threadIdx.x;   // over NTOT*128
    int node = (int)(i >> 7);
    int c = (int)(i & 127);
    float ecorr = 0.f;
#pragma unroll
    for (int d = 0; d < EDIM_; ++d) ecorr += ea5[node * EDIM_ + d] * We[d * 128 + c];
    float v = h[i] + inv_l[node] * ecorr + bf2f(qkvs[(long)node * 512 + 384 + c]);
    h[i] = fmaxf(v, 0.f);
}

// ---------------------------------------------------------------------------
// Row-wise softmax over NC columns, wave per row
// ---------------------------------------------------------------------------
template <int NC>
__global__ __launch_bounds__(256) void softmax_kernel(float* __restrict__ s) {
    int wave = threadIdx.x >> 6;
    int lane = threadIdx.x & 63;
    int row = blockIdx.x * 4 + wave;
    float* p = s + (long)row * NC;
    constexpr int PER = NC / 64;
    float v[PER];
    float mx = -INFINITY;
#pragma unroll
    for (int j = 0; j < PER; ++j) { v[j] = p[lane + j * 64]; mx = fmaxf(mx, v[j]); }
#pragma unroll
    for (int off = 32; off; off >>= 1) mx = fmaxf(mx, __shfl_xor(mx, off));
    float sm = 0.f;
#pragma unroll
    for (int j = 0; j < PER; ++j) { v[j] = expf(v[j] - mx); sm += v[j]; }
#pragma unroll
    for (int off = 32; off; off >>= 1) sm += __shfl_xor(sm, off);
    float inv = 1.f / sm;
#pragma unroll
    for (int j = 0; j < PER; ++j) p[lane + j * 64] = v[j] * inv;
}

// ---------------------------------------------------------------------------
// Sparse T1 = adj @ s1 via CSR-by-src
// ---------------------------------------------------------------------------
__global__ __launch_bounds__(256) void spmm_t1_kernel(const float* __restrict__ s1,
                                                      const int* __restrict__ ei_dst,
                                                      const int* __restrict__ rp_src,
                                                      const int* __restrict__ deg_src,
                                                      const int* __restrict__ eid_src,
                                                      float* __restrict__ T1) {
    int wave = threadIdx.x >> 6;
    int lane = threadIdx.x & 63;
    int node = blockIdx.x * 4 + wave;
    int start = rp_src[node], cnt = deg_src[node];
    float acc[4] = {0.f, 0.f, 0.f, 0.f};
    for (int t = 0; t < cnt; ++t) {
        int e = eid_src[start + t];
        int dst = ei_dst[e];
        const float* sr = s1 + (long)dst * K1C;
#pragma unroll
        for (int j = 0; j < 4; ++j) acc[j] += sr[lane + j * 64];
    }
    float* out = T1 + (long)node * K1C;
#pragma unroll
    for (int j = 0; j < 4; ++j) out[lane + j * 64] = acc[j];
}

// ---------------------------------------------------------------------------
// Pooled-adj normalization
// ---------------------------------------------------------------------------
template <int KC>
__global__ __launch_bounds__(256) void dinv_kernel(const float* __restrict__ adj,
                                                   float* __restrict__ dinv) {
    int wave = threadIdx.x >> 6;
    int lane = threadIdx.x & 63;
    int row = blockIdx.x * 4 + wave;
    int b = row / KC, r = row % KC;
    const float* p = adj + (long)b * KC * KC + (long)r * KC;
    float s = 0.f;
    for (int j = lane; j < KC; j += 64)
        if (j != r) s += p[j];
#pragma unroll
    for (int off = 32; off; off >>= 1) s += __shfl_xor(s, off);
    if (lane == 0) dinv[row] = 1.f / (sqrtf(s) + 1e-15f);
}

template <int KC>
__global__ __launch_bounds__(256) void scale_adj_kernel(float* __restrict__ adj,
                                                        const float* __restrict__ dinv) {
    long i = (long)blockIdx.x * 256 + threadIdx.x;
    int c = (int)(i % KC);
    long t = i / KC;
    int r = (int)(t % KC);
    int b = (int)(t / KC);
    float v = adj[i];
    v = (r == c) ? 0.f : v * dinv[b * KC + r] * dinv[b * KC + c];
    adj[i] = v;
}

// ---------------------------------------------------------------------------
// Readout
// ---------------------------------------------------------------------------
__global__ __launch_bounds__(128) void readout_kernel(const float* __restrict__ xd3,
                                                      const float* __restrict__ W_lin1,
                                                      const float* __restrict__ b_lin1,
                                                      const float* __restrict__ W_ro,
                                                      const float* __restrict__ b_ro,
                                                      float* __restrict__ out) {
    int b = blockIdx.x, t = threadIdx.x;
    __shared__ float g[128], g2[128], wred[2];
    const float* X = xd3 + (long)b * K2C * 128;
    float s = 0.f;
    for (int r = 0; r < K2C; ++r) s += X[r * 128 + t];
    g[t] = s * (1.f / (float)K2C);
    __syncthreads();
    float u = b_lin1[t];
    for (int k = 0; k < 128; ++k) u += g[k] * W_lin1[k * 128 + t];
    g2[t] = fmaxf(u, 0.f);
    __syncthreads();
    float p = g2[t] * W_ro[t];
#pragma unroll
    for (int off = 32; off; off >>= 1) p += __shfl_xor(p, off);
    if ((t & 63) == 0) wred[t >> 6] = p;
    __syncthreads();
    if (t == 0) {
        float tot = wred[0] + wred[1] + b_ro[0];
        out[b] = 1.f / (1.f + expf(-tot));
    }
}

// ---------------------------------------------------------------------------
extern "C" void kernel_launch(void* const* d_in, const int* in_sizes, int n_in,
                              void* d_out, int out_size, void* d_ws, size_t ws_size,
                              hipStream_t stream) {
    const float* x      = (const float*)d_in[0];
    const int*   ei     = (const int*)d_in[1];
    const float* eattr  = (const float*)d_in[2];
    const float* gamma  = (const float*)d_in[4];
    const float* beta   = (const float*)d_in[5];
    const float* Wq     = (const float*)d_in[6];
    const float* bq     = (const float*)d_in[7];
    const float* Wk     = (const float*)d_in[8];
    const float* bk     = (const float*)d_in[9];
    const float* Wv     = (const float*)d_in[10];
    const float* bv     = (const float*)d_in[11];
    const float* We     = (const float*)d_in[12];
    const float* Wskip  = (const float*)d_in[13];
    const float* bskip  = (const float*)d_in[14];
    const float* W_mlp1 = (const float*)d_in[15];
    const float* b_mlp1 = (const float*)d_in[16];
    const float* W2_rel = (const float*)d_in[17];
    const float* b2_rel = (const float*)d_in[18];
    const float* W2_root= (const float*)d_in[19];
    const float* W_mlp2 = (const float*)d_in[20];
    const float* b_mlp2 = (const float*)d_in[21];
    const float* W3_rel = (const float*)d_in[22];
    const float* b3_rel = (const float*)d_in[23];
    const float* W3_root= (const float*)d_in[24];
    const float* W_lin1 = (const float*)d_in[25];
    const float* b_lin1 = (const float*)d_in[26];
    const float* W_ro   = (const float*)d_in[27];
    const float* b_ro   = (const float*)d_in[28];
    float* out = (float*)d_out;

    char* w = (char*)d_ws;
    const size_t MB = 1ull << 20;
    // Workspace plan (peak 110 MB), lifetime-aliased (same as round 4).
    short* qkvs = (short*)(w + 0);          // [NTOT,512] bf16 32MB
    float* s1   = (float*)(w + 0);          // [NTOT,256] 32MB
    float* S    = (float*)(w + 32 * MB);    // [NTOT,512] 64MB
    short* P    = (short*)(w + 32 * MB);    // [NTOT,512] bf16 32MB
    float* T1   = (float*)(w + 32 * MB);    // [NTOT,256] 32MB
    float* tgc2 = (float*)(w + 32 * MB);    // [B,256,128] 8MB
    float* xd2  = (float*)(w + 40 * MB);    // [B,256,128] 8MB
    float* s2   = (float*)(w + 48 * MB);    // [B,256,128] 8MB
    float* t2   = (float*)(w + 56 * MB);    // [B,256,128] 8MB
    float* adj2 = (float*)(w + 0);          // [B,128,128] 4MB
    float* xp2  = (float*)(w + 4 * MB);     // [B,128,128] 4MB
    float* t3   = (float*)(w + 8 * MB);     // [B,128,128] 4MB
    float* xd3  = (float*)(w + 12 * MB);    // [B,128,128] 4MB
    float* h    = (float*)(w + 64 * MB);    // [NTOT,128] 16MB (agg then h)
    float* adj1 = (float*)(w + 80 * MB);    // [B,256,256] 16MB
    float* xp1  = (float*)(w + 96 * MB);    // [B,256,128] 8MB
    float* alpha = (float*)(w + 96 * MB);            // [E] 2MB (dead before xp1)
    float* linv  = (float*)(w + 98 * MB);            // [NTOT] 128KB  (l then 1/l)
    float* ea5   = (float*)(w + 98 * MB + 0x40000);  // [NTOT,5] 640KB
    float* qWe   = (float*)(w + 99 * MB);            // [NTOT,5] 640KB
    char* misc  = w + 104 * MB;
    float* W4     = (float*)(misc + 0x00000);
    float* bias4  = (float*)(misc + 0x40000);
    float* scale  = (float*)(misc + 0x41400);
    float* shift  = (float*)(misc + 0x41600);
    float* dinv1  = (float*)(misc + 0x42000);
    float* dinv2  = (float*)(misc + 0x52000);
    int* deg_src  = (int*)(misc + 0x60000);
    int* deg_dst  = (int*)(misc + 0x80000);
    int* rp_src   = (int*)(misc + 0xA0000);
    int* rp_dst   = (int*)(misc + 0xC0000);
    int* cur_src  = (int*)(misc + 0xE0000);
    int* cur_dst  = (int*)(misc + 0x100000);
    int* eid_src  = (int*)(misc + 0x120000);    // 2MB
    int* eid_dst  = (int*)(misc + 0x320000);    // 2MB
    float* psum   = (float*)(misc + 0x520000);  // [256,128] 128KB
    float* psq    = (float*)(misc + 0x540000);  // [256,128] 128KB

    hipMemsetAsync(deg_src, 0, 2 * NTOT * sizeof(int), stream);

    // 1. BatchNorm affine params (256 blocks, float4, partial buffers)
    bn_stats_kernel<<<256, 256, 0, stream>>>(x, psum, psq);
    bn_finalize_kernel<<<1, 128, 0, stream>>>(psum, psq, gamma, beta, scale, shift);

    // 2. Pack fused qkvs weights
    pack_w4_kernel<<<256, 256, 0, stream>>>(Wq, Wk, Wv, Wskip, bq, bk, bv, bskip, W4, bias4);

    // 3. CSR by src and dst (dst CSR no longer needed for attention; src CSR for spmm)
    hist_kernel<<<EDGES / 256, 256, 0, stream>>>(ei, deg_src, deg_dst);
    scan_kernel<<<1, 1024, 0, stream>>>(deg_src, rp_src, cur_src);
    scan_kernel<<<1, 1024, 0, stream>>>(deg_dst, rp_dst, cur_dst);
    scatter_kernel<<<EDGES / 256, 256, 0, stream>>>(ei, cur_src, cur_dst, eid_src, eid_dst);

    // 4. qkvs(bf16) = BN(x) @ [Wq|Wk|Wv|Wskip] + biases
    mgemm<false, true, false, false, true><<<dim3(4, 256, 1), 256, 0, stream>>>(
        x, W4, nullptr, nullptr, 0, bias4, qkvs, scale, shift,
        NTOT, 512, 128, 128, 512, 512, 0, 0, 0);

    // 5. qWe = q @ We^T / sqrt(H)  (thread per (node,d))
    qwe_kernel<<<(NTOT * EDIM_) / 256, 256, 0, stream>>>(qkvs, We, qWe);

    // 6. S = (Q @ K^T) / sqrt(H) per graph (dense, MFMA)
    bgemm<true><<<dim3(4, 4, BGRAPH), 256, 0, stream>>>(
        qkvs + 0, qkvs + 128, S, 0.08838834764831845f,
        NNODE, NNODE, 128, 512, 512, 512,
        (long)NNODE * 512, (long)NNODE * 512, (long)NNODE * NNODE);

    // 7. Edge-parallel softmax accumulation, then invert l
    hipMemsetAsync(linv, 0, 1 * MB - 0x40000 + 0xA0000, stream);  // linv..ea5 region
    esoftmax_edge_kernel<<<EDGES / 256, 256, 0, stream>>>(S, ei, eattr, qWe, alpha, linv, ea5);
    invl_kernel<<<NTOT / 256, 256, 0, stream>>>(linv);

    // 8. Build P (bf16, CAS-accumulate) and agg = P @ V; assemble h
    hipMemsetAsync(P, 0, (size_t)NTOT * 512 * sizeof(short), stream);
    pbuild_edge_kernel<<<EDGES / 256, 256, 0, stream>>>(alpha, linv, ei, P);
    bgemm<false><<<dim3(1, 4, BGRAPH), 256, 0, stream>>>(
        P, qkvs + 256, h, 1.0f,
        NNODE, 128, NNODE, 512, 512, 128,
        (long)NNODE * 512, (long)NNODE * 512, (long)NNODE * 128);
    hassemble_kernel<<<(NTOT * 128) / 256, 256, 0, stream>>>(h, ea5, linv, We, qkvs);

    // 9. s1 = softmax(h @ W_mlp1 + b_mlp1)
    mgemm<false, false, false, false, false><<<dim3(2, 256, 1), 256, 0, stream>>>(
        h, W_mlp1, nullptr, nullptr, 0, b_mlp1, s1, nullptr, nullptr,
        NTOT, K1C, 128, 128, K1C, K1C, 0, 0, 0);
    softmax_kernel<K1C><<<NTOT / 4, 256, 0, stream>>>(s1);

    // 10. T1 = adj @ s1 (sparse)
    spmm_t1_kernel<<<NTOT / 4, 256, 0, stream>>>(s1, ei + EDGES, rp_src, deg_src, eid_src, T1);

    // 11. adj1 = s1^T T1 ; xp1 = s1^T h
    mgemm<true, false, false, false, false><<<dim3(2, 2, BGRAPH), 256, 0, stream>>>(
        s1, T1, nullptr, nullptr, 0, nullptr, adj1, nullptr, nullptr,
        K1C, K1C, NNODE, K1C, K1C, K1C,
        (long)NNODE * K1C, (long)NNODE * K1C, (long)K1C * K1C);
    mgemm<true, false, false, false, false><<<dim3(1, 2, BGRAPH), 256, 0, stream>>>(
        s1, h, nullptr, nullptr, 0, nullptr, xp1, nullptr, nullptr,
        K1C, 128, NNODE, K1C, 128, 128,
        (long)NNODE * K1C, (long)NNODE * 128, (long)K1C * 128);

    // 12. Normalize adj1
    dinv_kernel<K1C><<<(BGRAPH * K1C) / 4, 256, 0, stream>>>(adj1, dinv1);
    scale_adj_kernel<K1C><<<(BGRAPH * K1C * K1C) / 256, 256, 0, stream>>>(adj1, dinv1);

    // 13. GraphConv2
    mgemm<false, false, false, false, false><<<dim3(1, 2, BGRAPH), 256, 0, stream>>>(
        adj1, xp1, nullptr, nullptr, 0, nullptr, tgc2, nullptr, nullptr,
        K1C, 128, K1C, K1C, 128, 128,
        (long)K1C * K1C, (long)K1C * 128, (long)K1C * 128);
    mgemm<false, false, true, true, false><<<dim3(1, 128, 1), 256, 0, stream>>>(
        tgc2, W2_rel, xp1, W2_root, 128, b2_rel, xd2, nullptr, nullptr,
        BGRAPH * K1C, 128, 256, 128, 128, 128, 0, 0, 0);

    // 14. s2 = softmax(xd2 @ W_mlp2 + b_mlp2)
    mgemm<false, false, false, false, false><<<dim3(1, 128, 1), 256, 0, stream>>>(
        xd2, W_mlp2, nullptr, nullptr, 0, b_mlp2, s2, nullptr, nullptr,
        BGRAPH * K1C, K2C, 128, 128, K2C, K2C, 0, 0, 0);
    softmax_kernel<K2C><<<(BGRAPH * K1C) / 4, 256, 0, stream>>>(s2);

    // 15. Pool2
    mgemm<false, false, false, false, false><<<dim3(1, 2, BGRAPH), 256, 0, stream>>>(
        adj1, s2, nullptr, nullptr, 0, nullptr, t2, nullptr, nullptr,
        K1C, K2C, K1C, K1C, K2C, K2C,
        (long)K1C * K1C, (long)K1C * K2C, (long)K1C * K2C);
    mgemm<true, false, false, false, false><<<dim3(1, 1, BGRAPH), 256, 0, stream>>>(
        s2, t2, nullptr, nullptr, 0, nullptr, adj2, nullptr, nullptr,
        K2C, K2C, K1C, K2C, K2C, K2C,
        (long)K1C * K2C, (long)K1C * K2C, (long)K2C * K2C);
    mgemm<true, false, false, false, false><<<dim3(1, 1, BGRAPH), 256, 0, stream>>>(
        s2, xd2, nullptr, nullptr, 0, nullptr, xp2, nullptr, nullptr,
        K2C, 128, K1C, K2C, 128, 128,
        (long)K1C * K2C, (long)K1C * 128, (long)K2C * 128);

    // 16. Normalize adj2
    dinv_kernel<K2C><<<(BGRAPH * K2C) / 4, 256, 0, stream>>>(adj2, dinv2);
    scale_adj_kernel<K2C><<<(BGRAPH * K2C * K2C) / 256, 256, 0, stream>>>(adj2, dinv2);

    // 17. GraphConv3
    mgemm<false, false, false, false, false><<<dim3(1, 1, BGRAPH), 256, 0, stream>>>(
        adj2, xp2, nullptr, nullptr, 0, nullptr, t3, nullptr, nullptr,
        K2C, 128, K2C, K2C, 128, 128,
        (long)K2C * K2C, (long)K2C * 128, (long)K2C * 128);
    mgemm<false, false, false, true, false><<<dim3(1, 64, 1), 256, 0, stream>>>(
        t3, W3_rel, xp2, W3_root, 128, b3_rel, xd3, nullptr, nullptr,
        BGRAPH * K2C, 128, 256, 128, 128, 128, 0, 0, 0);

    // 18. Readout
    readout_kernel<<<BGRAPH, 128, 0, stream>>>(xd3, W_lin1, b_lin1, W_ro, b_ro, out);

    (void)in_sizes; (void)n_in; (void)out_size; (void)ws_size;
}

// Round 6
// 664.209 us; speedup vs baseline: 1.2064x; 1.2064x over previous
//
#include <hip/hip_runtime.h>
#include <math.h>

// Problem constants
#define BGRAPH 64
#define NNODE  512
#define NTOT   32768        // BGRAPH*NNODE
#define CIN    128
#define HDIM   128
#define EDIM_  5
#define EDGES  524288
#define K1C    256
#define K2C    128

using f32x4 = __attribute__((ext_vector_type(4))) float;
using s16x8 = __attribute__((ext_vector_type(8))) short;

__device__ __forceinline__ short f2bf(float f) {
    union { float f; unsigned u; } v; v.f = f;
    unsigned r = v.u + 0x7fffu + ((v.u >> 16) & 1u);   // RNE
    return (short)(r >> 16);
}
__device__ __forceinline__ float bf2f(short s) {
    union { unsigned u; float f; } v; v.u = ((unsigned)(unsigned short)s) << 16;
    return v.f;
}

// ---------------------------------------------------------------------------
// BatchNorm statistics: 256 blocks, float4 loads, per-block partials (no atomics)
// ---------------------------------------------------------------------------
__global__ __launch_bounds__(256) void bn_stats_kernel(const float* __restrict__ x,
                                                       float* __restrict__ psum,
                                                       float* __restrict__ psq) {
    int tid = threadIdx.x, bid = blockIdx.x;
    long idx0 = (long)bid * 256 + tid;            // float4 index
    float4 s = {0.f, 0.f, 0.f, 0.f}, q = {0.f, 0.f, 0.f, 0.f};
#pragma unroll
    for (int it = 0; it < 16; ++it) {             // 256*256*16*4 = NTOT*CIN
        float4 v = *(const float4*)(x + (idx0 + (long)it * 65536) * 4);
        s.x += v.x; s.y += v.y; s.z += v.z; s.w += v.w;
        q.x += v.x * v.x; q.y += v.y * v.y; q.z += v.z * v.z; q.w += v.w * v.w;
    }
    __shared__ float ss[128], sq[128];
    if (tid < 128) { ss[tid] = 0.f; sq[tid] = 0.f; }
    __syncthreads();
    int c0 = (tid & 31) * 4;                      // fixed channels per thread
    atomicAdd(&ss[c0 + 0], s.x); atomicAdd(&ss[c0 + 1], s.y);
    atomicAdd(&ss[c0 + 2], s.z); atomicAdd(&ss[c0 + 3], s.w);
    atomicAdd(&sq[c0 + 0], q.x); atomicAdd(&sq[c0 + 1], q.y);
    atomicAdd(&sq[c0 + 2], q.z); atomicAdd(&sq[c0 + 3], q.w);
    __syncthreads();
    if (tid < 128) {
        psum[bid * 128 + tid] = ss[tid];
        psq[bid * 128 + tid]  = sq[tid];
    }
}

__global__ __launch_bounds__(128) void bn_finalize_kernel(const float* __restrict__ psum,
                                                          const float* __restrict__ psq,
                                                          const float* __restrict__ gamma,
                                                          const float* __restrict__ beta,
                                                          float* __restrict__ scale,
                                                          float* __restrict__ shift) {
    int c = threadIdx.x;
    float s = 0.f, q = 0.f;
    for (int b = 0; b < 256; ++b) { s += psum[b * 128 + c]; q += psq[b * 128 + c]; }
    float mu  = s / (float)NTOT;
    float var = q / (float)NTOT - mu * mu;
    float rstd = rsqrtf(var + 1e-5f);
    float sc = gamma[c] * rstd;
    scale[c] = sc;
    shift[c] = beta[c] - mu * sc;
}

// ---------------------------------------------------------------------------
// Pack Wq|Wk|Wv|Wskip into [128,512] and biases into [512]
// ---------------------------------------------------------------------------
__global__ __launch_bounds__(256) void pack_w4_kernel(const float* __restrict__ Wq, const float* __restrict__ Wk,
                                                      const float* __restrict__ Wv, const float* __restrict__ Ws,
                                                      const float* __restrict__ bq, const float* __restrict__ bk,
                                                      const float* __restrict__ bv, const float* __restrict__ bs,
                                                      float* __restrict__ W4, float* __restrict__ bias4) {
    int i = blockIdx.x * 256 + threadIdx.x;
    if (i < 128 * 512) {
        int k = i / 512, j = i % 512;
        float v;
        if (j < 128)      v = Wq[k * 128 + j];
        else if (j < 256) v = Wk[k * 128 + (j - 128)];
        else if (j < 384) v = Wv[k * 128 + (j - 256)];
        else              v = Ws[k * 128 + (j - 384)];
        W4[i] = v;
    }
    if (i < 512) {
        float v;
        if (i < 128)      v = bq[i];
        else if (i < 256) v = bk[i - 128];
        else if (i < 384) v = bv[i - 256];
        else              v = bs[i - 384];
        bias4[i] = v;
    }
}

// ---------------------------------------------------------------------------
// CSR build: histogram, scan, scatter
// ---------------------------------------------------------------------------
__global__ __launch_bounds__(256) void hist_kernel(const int* __restrict__ ei,
                                                   int* __restrict__ deg_src,
                                                   int* __restrict__ deg_dst) {
    int e = blockIdx.x * 256 + threadIdx.x;
    if (e < EDGES) {
        atomicAdd(&deg_src[ei[e]], 1);
        atomicAdd(&deg_dst[ei[EDGES + e]], 1);
    }
}

__global__ __launch_bounds__(1024) void scan_kernel(const int* __restrict__ deg,
                                                    int* __restrict__ rowptr,
                                                    int* __restrict__ cursor) {
    __shared__ int part[1024];
    int tid = threadIdx.x;
    int base = tid * 32;
    int s = 0;
    for (int i = 0; i < 32; ++i) s += deg[base + i];
    part[tid] = s;
    __syncthreads();
    for (int off = 1; off < 1024; off <<= 1) {
        int v = part[tid];
        int add = (tid >= off) ? part[tid - off] : 0;
        __syncthreads();
        part[tid] = v + add;
        __syncthreads();
    }
    int run = (tid == 0) ? 0 : part[tid - 1];
    for (int i = 0; i < 32; ++i) {
        rowptr[base + i] = run;
        cursor[base + i] = run;
        run += deg[base + i];
    }
}

__global__ __launch_bounds__(256) void scatter_kernel(const int* __restrict__ ei,
                                                      int* __restrict__ cur_src, int* __restrict__ cur_dst,
                                                      int* __restrict__ eid_src, int* __restrict__ eid_dst) {
    int e = blockIdx.x * 256 + threadIdx.x;
    if (e < EDGES) {
        int s = ei[e], d = ei[EDGES + e];
        eid_src[atomicAdd(&cur_src[s], 1)] = e;
        eid_dst[atomicAdd(&cur_dst[d], 1)] = e;
    }
}

// ---------------------------------------------------------------------------
// BF16 MFMA GEMM, fp32 global inputs (converted at staging).
// OBF16: epilogue stores bf16 instead of fp32.
// ---------------------------------------------------------------------------
template <bool TRANS_A, bool AFFINE, bool RELU, bool DUAL, bool OBF16>
__global__ __launch_bounds__(256) void mgemm(const float* __restrict__ A,
                                             const float* __restrict__ B,
                                             const float* __restrict__ A2,
                                             const float* __restrict__ B2,
                                             int Ksplit,
                                             const float* __restrict__ bias,
                                             void* __restrict__ Cv,
                                             const float* __restrict__ scale,
                                             const float* __restrict__ shift,
                                             int M, int Nc, int K,
                                             int lda, int ldb, int ldc,
                                             long sA, long sB, long sC) {
    __shared__ __align__(16) short As[128 * 40];
    __shared__ __align__(16) short Bs[128 * 40];
    A += (long)blockIdx.z * sA;
    B += (long)blockIdx.z * sB;
    float* C = (float*)Cv + (OBF16 ? 0 : (long)blockIdx.z * sC);
    short* Cs = (short*)Cv + (OBF16 ? (long)blockIdx.z * sC : 0);
    const int m0 = blockIdx.y * 128, n0 = blockIdx.x * 128;
    const int tid = threadIdx.x;
    const int lane16 = tid & 15;
    const int quad = (tid & 63) >> 4;
    const int wrow = (tid >> 6) >> 1, wcol = (tid >> 6) & 1;

    f32x4 acc[4][4] = {};

    for (int k0 = 0; k0 < K; k0 += 32) {
        const float* Au = A; const float* Bu = B; int ku = k0;
        if (DUAL && k0 >= Ksplit) { Au = A2; Bu = B2; ku = k0 - Ksplit; }

        if (!TRANS_A) {
#pragma unroll
            for (int p = 0; p < 4; ++p) {
                int idx = tid + p * 256;
                int row = idx >> 3, c4 = idx & 7;
                float4 v = *(const float4*)(Au + (long)(m0 + row) * lda + ku + c4 * 4);
                if (AFFINE) {
                    int k = ku + c4 * 4;
                    v.x = v.x * scale[k] + shift[k];
                    v.y = v.y * scale[k + 1] + shift[k + 1];
                    v.z = v.z * scale[k + 2] + shift[k + 2];
                    v.w = v.w * scale[k + 3] + shift[k + 3];
                }
                *(short4*)&As[row * 40 + c4 * 4] =
                    make_short4(f2bf(v.x), f2bf(v.y), f2bf(v.z), f2bf(v.w));
            }
        } else {
            int c4 = tid & 31, g = tid >> 5;
            const float* src = Au + (long)(ku + g * 4) * lda + m0 + c4 * 4;
            float4 r0 = *(const float4*)(src);
            float4 r1 = *(const float4*)(src + lda);
            float4 r2 = *(const float4*)(src + 2 * lda);
            float4 r3 = *(const float4*)(src + 3 * lda);
            short* d = &As[(c4 * 4) * 40 + g * 4];
            *(short4*)(d + 0 * 40) = make_short4(f2bf(r0.x), f2bf(r1.x), f2bf(r2.x), f2bf(r3.x));
            *(short4*)(d + 1 * 40) = make_short4(f2bf(r0.y), f2bf(r1.y), f2bf(r2.y), f2bf(r3.y));
            *(short4*)(d + 2 * 40) = make_short4(f2bf(r0.z), f2bf(r1.z), f2bf(r2.z), f2bf(r3.z));
            *(short4*)(d + 3 * 40) = make_short4(f2bf(r0.w), f2bf(r1.w), f2bf(r2.w), f2bf(r3.w));
        }
        {
            int c4 = tid & 31, g = tid >> 5;
            const float* src = Bu + (long)(ku + g * 4) * ldb + n0 + c4 * 4;
            float4 r0 = *(const float4*)(src);
            float4 r1 = *(const float4*)(src + ldb);
            float4 r2 = *(const float4*)(src + 2 * ldb);
            float4 r3 = *(const float4*)(src + 3 * ldb);
            short* d = &Bs[(c4 * 4) * 40 + g * 4];
            *(short4*)(d + 0 * 40) = make_short4(f2bf(r0.x), f2bf(r1.x), f2bf(r2.x), f2bf(r3.x));
            *(short4*)(d + 1 * 40) = make_short4(f2bf(r0.y), f2bf(r1.y), f2bf(r2.y), f2bf(r3.y));
            *(short4*)(d + 2 * 40) = make_short4(f2bf(r0.z), f2bf(r1.z), f2bf(r2.z), f2bf(r3.z));
            *(short4*)(d + 3 * 40) = make_short4(f2bf(r0.w), f2bf(r1.w), f2bf(r2.w), f2bf(r3.w));
        }
        __syncthreads();

        s16x8 af[4], bf[4];
#pragma unroll
        for (int t = 0; t < 4; ++t) {
            af[t] = *(const s16x8*)&As[(wrow * 64 + t * 16 + lane16) * 40 + quad * 8];
            bf[t] = *(const s16x8*)&Bs[(wcol * 64 + t * 16 + lane16) * 40 + quad * 8];
        }
#pragma unroll
        for (int i = 0; i < 4; ++i)
#pragma unroll
            for (int j = 0; j < 4; ++j)
                acc[i][j] = __builtin_amdgcn_mfma_f32_16x16x32_bf16(af[i], bf[j], acc[i][j], 0, 0, 0);
        __syncthreads();
    }

#pragma unroll
    for (int i = 0; i < 4; ++i) {
        int gm = m0 + wrow * 64 + i * 16 + quad * 4;
#pragma unroll
        for (int j = 0; j < 4; ++j) {
            int gn = n0 + wcol * 64 + j * 16 + lane16;
            float bv = bias ? bias[gn] : 0.f;
#pragma unroll
            for (int r = 0; r < 4; ++r) {
                float val = acc[i][j][r] + bv;
                if (RELU) val = fmaxf(val, 0.f);
                if (OBF16) Cs[(long)(gm + r) * ldc + gn] = f2bf(val);
                else       C[(long)(gm + r) * ldc + gn] = val;
            }
        }
    }
}

// ---------------------------------------------------------------------------
// BF16-input MFMA GEMM (no conversion): C = outscale * (A @ B), batched.
// OBF16: store bf16 C.
// ---------------------------------------------------------------------------
template <bool TRANS_B, bool OBF16>
__global__ __launch_bounds__(256) void bgemm(const short* __restrict__ A,
                                             const short* __restrict__ B,
                                             void* __restrict__ Cv,
                                             float outscale,
                                             int M, int Nc, int K,
                                             int lda, int ldb, int ldc,
                                             long sA, long sB, long sC) {
    __shared__ __align__(16) short As[128 * 40];
    __shared__ __align__(16) short Bs[128 * 40];
    A += (long)blockIdx.z * sA;
    B += (long)blockIdx.z * sB;
    float* C = (float*)Cv + (OBF16 ? 0 : (long)blockIdx.z * sC);
    short* Cs = (short*)Cv + (OBF16 ? (long)blockIdx.z * sC : 0);
    const int m0 = blockIdx.y * 128, n0 = blockIdx.x * 128;
    const int tid = threadIdx.x;
    const int lane16 = tid & 15;
    const int quad = (tid & 63) >> 4;
    const int wrow = (tid >> 6) >> 1, wcol = (tid >> 6) & 1;

    f32x4 acc[4][4] = {};

    for (int k0 = 0; k0 < K; k0 += 32) {
#pragma unroll
        for (int p = 0; p < 2; ++p) {
            int u = tid + p * 256;
            int row = u >> 2, g = u & 3;
            *(s16x8*)&As[row * 40 + g * 8] =
                *(const s16x8*)(A + (long)(m0 + row) * lda + k0 + g * 8);
        }
        if (TRANS_B) {
#pragma unroll
            for (int p = 0; p < 2; ++p) {
                int u = tid + p * 256;
                int row = u >> 2, g = u & 3;
                *(s16x8*)&Bs[row * 40 + g * 8] =
                    *(const s16x8*)(B + (long)(n0 + row) * ldb + k0 + g * 8);
            }
        } else {
            int c4 = tid & 31, g = tid >> 5;
            const short* src = B + (long)(k0 + g * 4) * ldb + n0 + c4 * 4;
            short4 r0 = *(const short4*)(src);
            short4 r1 = *(const short4*)(src + ldb);
            short4 r2 = *(const short4*)(src + 2 * ldb);
            short4 r3 = *(const short4*)(src + 3 * ldb);
            short* d = &Bs[(c4 * 4) * 40 + g * 4];
            *(short4*)(d + 0 * 40) = make_short4(r0.x, r1.x, r2.x, r3.x);
            *(short4*)(d + 1 * 40) = make_short4(r0.y, r1.y, r2.y, r3.y);
            *(short4*)(d + 2 * 40) = make_short4(r0.z, r1.z, r2.z, r3.z);
            *(short4*)(d + 3 * 40) = make_short4(r0.w, r1.w, r2.w, r3.w);
        }
        __syncthreads();

        s16x8 af[4], bf[4];
#pragma unroll
        for (int t = 0; t < 4; ++t) {
            af[t] = *(const s16x8*)&As[(wrow * 64 + t * 16 + lane16) * 40 + quad * 8];
            bf[t] = *(const s16x8*)&Bs[(wcol * 64 + t * 16 + lane16) * 40 + quad * 8];
        }
#pragma unroll
        for (int i = 0; i < 4; ++i)
#pragma unroll
            for (int j = 0; j < 4; ++j)
                acc[i][j] = __builtin_amdgcn_mfma_f32_16x16x32_bf16(af[i], bf[j], acc[i][j], 0, 0, 0);
        __syncthreads();
    }

#pragma unroll
    for (int i = 0; i < 4; ++i) {
        int gm = m0 + wrow * 64 + i * 16 + quad * 4;
#pragma unroll
        for (int j = 0; j < 4; ++j) {
            int gn = n0 + wcol * 64 + j * 16 + lane16;
#pragma unroll
            for (int r = 0; r < 4; ++r) {
                float val = acc[i][j][r] * outscale;
                if (OBF16) Cs[(long)(gm + r) * ldc + gn] = f2bf(val);
                else       C[(long)(gm + r) * ldc + gn] = val;
            }
        }
    }
}

// ---------------------------------------------------------------------------
// qWe[node][d] = (q[node,:] . We[d,:]) / sqrt(H) — thread per (node,d)
// ---------------------------------------------------------------------------
__global__ __launch_bounds__(256) void qwe_kernel(const short* __restrict__ qkvs,
                                                  const float* __restrict__ We,
                                                  float* __restrict__ qWe) {
    __shared__ float sWe[EDIM_ * 128];
    for (int i = threadIdx.x; i < EDIM_ * 128; i += 256) sWe[i] = We[i];
    __syncthreads();
    int i = blockIdx.x * 256 + threadIdx.x;        // < NTOT*5
    int node = i / 5, d = i - node * 5;
    const s16x8* row = (const s16x8*)(qkvs + (long)node * 512);
    float acc = 0.f;
#pragma unroll
    for (int g = 0; g < 16; ++g) {
        s16x8 v = row[g];
#pragma unroll
        for (int j = 0; j < 8; ++j) acc += bf2f(v[j]) * sWe[d * 128 + g * 8 + j];
    }
    qWe[i] = acc * 0.08838834764831845f;           // 1/sqrt(128)
}

// ---------------------------------------------------------------------------
// Fused edge-softmax + P-row build. 16 lanes per dst node, 16 nodes/block.
// LDS fp32 row per node; zero global atomics. S is bf16 [NTOT,512].
// Outputs: P[dst,src] = alpha (bf16, normalized), ea5n[dst][5] = (Σ w·ea)/l.
// ---------------------------------------------------------------------------
__global__ __launch_bounds__(256) void attn_fuse_kernel(const short* __restrict__ S,
                                                        const int* __restrict__ ei,
                                                        const float* __restrict__ eattr,
                                                        const float* __restrict__ qWe,
                                                        const int* __restrict__ rp_dst,
                                                        const int* __restrict__ deg_dst,
                                                        const int* __restrict__ eid_dst,
                                                        short* __restrict__ P,
                                                        float* __restrict__ ea5n) {
    __shared__ float rows[16][512];                // 32 KB
    int g = threadIdx.x >> 4;
    int lane = threadIdx.x & 15;
    int node = blockIdx.x * 16 + g;
    float* row = rows[g];
    for (int i = lane; i < 512; i += 16) row[i] = 0.f;
    float qw[EDIM_];
#pragma unroll
    for (int d = 0; d < EDIM_; ++d) qw[d] = qWe[node * EDIM_ + d];
    int start = rp_dst[node], cnt = deg_dst[node];
    const short* Srow = S + (long)node * 512;
    float lsum = 0.f, a5[EDIM_] = {};
    for (int t = lane; t < cnt; t += 16) {
        int e = eid_dst[start + t];
        int src = ei[e] & 511;
        float lg = bf2f(Srow[src]);
        float ea[EDIM_];
#pragma unroll
        for (int d = 0; d < EDIM_; ++d) { ea[d] = eattr[e * EDIM_ + d]; lg += ea[d] * qw[d]; }
        float wv = expf(lg);                       // logits are O(1): no max-pass needed
        lsum += wv;
#pragma unroll
        for (int d = 0; d < EDIM_; ++d) a5[d] += wv * ea[d];
        atomicAdd(&row[src], wv);                  // LDS atomic (duplicate-src safe)
    }
    // butterfly over the 16-lane group (all lanes end with totals)
#pragma unroll
    for (int off = 8; off; off >>= 1) {
        lsum += __shfl_xor(lsum, off);
#pragma unroll
        for (int d = 0; d < EDIM_; ++d) a5[d] += __shfl_xor(a5[d], off);
    }
    float inv = (lsum > 0.f) ? 1.f / lsum : 0.f;
    if (lane < EDIM_) {
        float v = lane == 0 ? a5[0] : lane == 1 ? a5[1] : lane == 2 ? a5[2]
                : lane == 3 ? a5[3] : a5[4];
        ea5n[node * EDIM_ + lane] = v * inv;
    }
    // normalized bf16 P row, coalesced packed-pair stores
    unsigned* Pr = (unsigned*)(P + (long)node * 512);
    for (int i = lane; i < 256; i += 16) {
        float v0 = row[2 * i] * inv, v1 = row[2 * i + 1] * inv;
        unsigned pack = (unsigned)(unsigned short)f2bf(v0)
                      | ((unsigned)(unsigned short)f2bf(v1) << 16);
        Pr[i] = pack;
    }
}

// ---------------------------------------------------------------------------
// h = relu(agg + ea5n @ We + skip)   (in place over agg; ea5n pre-normalized)
// ---------------------------------------------------------------------------
__global__ __launch_bounds__(256) void hassemble_kernel(float* __restrict__ h,
                                                        const float* __restrict__ ea5n,
                                                        const float* __restrict__ We,
                                                        const short* __restrict__ qkvs) {
    long i = (long)blockIdx.x * 256 + threadIdx.x;   // over NTOT*128
    int node = (int)(i >> 7);
    int c = (int)(i & 127);
    float ecorr = 0.f;
#pragma unroll
    for (int d = 0; d < EDIM_; ++d) ecorr += ea5n[node * EDIM_ + d] * We[d * 128 + c];
    float v = h[i] + ecorr + bf2f(qkvs[(long)node * 512 + 384 + c]);
    h[i] = fmaxf(v, 0.f);
}

// ---------------------------------------------------------------------------
// Row-wise softmax over NC columns, wave per row
// ---------------------------------------------------------------------------
template <int NC>
__global__ __launch_bounds__(256) void softmax_kernel(float* __restrict__ s) {
    int wave = threadIdx.x >> 6;
    int lane = threadIdx.x & 63;
    int row = blockIdx.x * 4 + wave;
    float* p = s + (long)row * NC;
    constexpr int PER = NC / 64;
    float v[PER];
    float mx = -INFINITY;
#pragma unroll
    for (int j = 0; j < PER; ++j) { v[j] = p[lane + j * 64]; mx = fmaxf(mx, v[j]); }
#pragma unroll
    for (int off = 32; off; off >>= 1) mx = fmaxf(mx, __shfl_xor(mx, off));
    float sm = 0.f;
#pragma unroll
    for (int j = 0; j < PER; ++j) { v[j] = expf(v[j] - mx); sm += v[j]; }
#pragma unroll
    for (int off = 32; off; off >>= 1) sm += __shfl_xor(sm, off);
    float inv = 1.f / sm;
#pragma unroll
    for (int j = 0; j < PER; ++j) p[lane + j * 64] = v[j] * inv;
}

// ---------------------------------------------------------------------------
// Sparse T1 = adj @ s1 via CSR-by-src
// ---------------------------------------------------------------------------
__global__ __launch_bounds__(256) void spmm_t1_kernel(const float* __restrict__ s1,
                                                      const int* __restrict__ ei_dst,
                                                      const int* __restrict__ rp_src,
                                                      const int* __restrict__ deg_src,
                                                      const int* __restrict__ eid_src,
                                                      float* __restrict__ T1) {
    int wave = threadIdx.x >> 6;
    int lane = threadIdx.x & 63;
    int node = blockIdx.x * 4 + wave;
    int start = rp_src[node], cnt = deg_src[node];
    float acc[4] = {0.f, 0.f, 0.f, 0.f};
    for (int t = 0; t < cnt; ++t) {
        int e = eid_src[start + t];
        int dst = ei_dst[e];
        const float* sr = s1 + (long)dst * K1C;
#pragma unroll
        for (int j = 0; j < 4; ++j) acc[j] += sr[lane + j * 64];
    }
    float* out = T1 + (long)node * K1C;
#pragma unroll
    for (int j = 0; j < 4; ++j) out[lane + j * 64] = acc[j];
}

// ---------------------------------------------------------------------------
// Pooled-adj normalization
// ---------------------------------------------------------------------------
template <int KC>
__global__ __launch_bounds__(256) void dinv_kernel(const float* __restrict__ adj,
                                                   float* __restrict__ dinv) {
    int wave = threadIdx.x >> 6;
    int lane = threadIdx.x & 63;
    int row = blockIdx.x * 4 + wave;
    int b = row / KC, r = row % KC;
    const float* p = adj + (long)b * KC * KC + (long)r * KC;
    float s = 0.f;
    for (int j = lane; j < KC; j += 64)
        if (j != r) s += p[j];
#pragma unroll
    for (int off = 32; off; off >>= 1) s += __shfl_xor(s, off);
    if (lane == 0) dinv[row] = 1.f / (sqrtf(s) + 1e-15f);
}

template <int KC>
__global__ __launch_bounds__(256) void scale_adj_kernel(float* __restrict__ adj,
                                                        const float* __restrict__ dinv) {
    long i = (long)blockIdx.x * 256 + threadIdx.x;
    int c = (int)(i % KC);
    long t = i / KC;
    int r = (int)(t % KC);
    int b = (int)(t / KC);
    float v = adj[i];
    v = (r == c) ? 0.f : v * dinv[b * KC + r] * dinv[b * KC + c];
    adj[i] = v;
}

// ---------------------------------------------------------------------------
// Readout
// ---------------------------------------------------------------------------
__global__ __launch_bounds__(128) void readout_kernel(const float* __restrict__ xd3,
                                                      const float* __restrict__ W_lin1,
                                                      const float* __restrict__ b_lin1,
                                                      const float* __restrict__ W_ro,
                                                      const float* __restrict__ b_ro,
                                                      float* __restrict__ out) {
    int b = blockIdx.x, t = threadIdx.x;
    __shared__ float g[128], g2[128], wred[2];
    const float* X = xd3 + (long)b * K2C * 128;
    float s = 0.f;
    for (int r = 0; r < K2C; ++r) s += X[r * 128 + t];
    g[t] = s * (1.f / (float)K2C);
    __syncthreads();
    float u = b_lin1[t];
    for (int k = 0; k < 128; ++k) u += g[k] * W_lin1[k * 128 + t];
    g2[t] = fmaxf(u, 0.f);
    __syncthreads();
    float p = g2[t] * W_ro[t];
#pragma unroll
    for (int off = 32; off; off >>= 1) p += __shfl_xor(p, off);
    if ((t & 63) == 0) wred[t >> 6] = p;
    __syncthreads();
    if (t == 0) {
        float tot = wred[0] + wred[1] + b_ro[0];
        out[b] = 1.f / (1.f + expf(-tot));
    }
}

// ---------------------------------------------------------------------------
extern "C" void kernel_launch(void* const* d_in, const int* in_sizes, int n_in,
                              void* d_out, int out_size, void* d_ws, size_t ws_size,
                              hipStream_t stream) {
    const float* x      = (const float*)d_in[0];
    const int*   ei     = (const int*)d_in[1];
    const float* eattr  = (const float*)d_in[2];
    const float* gamma  = (const float*)d_in[4];
    const float* beta   = (const float*)d_in[5];
    const float* Wq     = (const float*)d_in[6];
    const float* bq     = (const float*)d_in[7];
    const float* Wk     = (const float*)d_in[8];
    const float* bk     = (const float*)d_in[9];
    const float* Wv     = (const float*)d_in[10];
    const float* bv     = (const float*)d_in[11];
    const float* We     = (const float*)d_in[12];
    const float* Wskip  = (const float*)d_in[13];
    const float* bskip  = (const float*)d_in[14];
    const float* W_mlp1 = (const float*)d_in[15];
    const float* b_mlp1 = (const float*)d_in[16];
    const float* W2_rel = (const float*)d_in[17];
    const float* b2_rel = (const float*)d_in[18];
    const float* W2_root= (const float*)d_in[19];
    const float* W_mlp2 = (const float*)d_in[20];
    const float* b_mlp2 = (const float*)d_in[21];
    const float* W3_rel = (const float*)d_in[22];
    const float* b3_rel = (const float*)d_in[23];
    const float* W3_root= (const float*)d_in[24];
    const float* W_lin1 = (const float*)d_in[25];
    const float* b_lin1 = (const float*)d_in[26];
    const float* W_ro   = (const float*)d_in[27];
    const float* b_ro   = (const float*)d_in[28];
    float* out = (float*)d_out;

    char* w = (char*)d_ws;
    const size_t MB = 1ull << 20;
    // Workspace plan (peak 110 MB), lifetime-aliased:
    //  [0,32)   qkvs bf16 (steps 4-8) → s1 fp32 (9-11) → adj2/xp2/t3/xd3 (15+)
    //  [32,64)  S bf16 (6-7) → h fp32 [32,48) (8-11) ; T1 [48,80) (10-11)
    //           → tgc2[48,56) xd2[56,64) s2[64,72) t2[72,80) (13+)
    //  [64,96)  P bf16 (7-8) → (s2/t2 above after P dead)
    //  [80,96)  adj1 (11-15)
    //  [96,104) qWe/ea5n (5-8) → xp1 (11-15)
    //  [104,110) misc
    short* qkvs = (short*)(w + 0);          // [NTOT,512] bf16 32MB
    float* s1   = (float*)(w + 0);          // [NTOT,256] 32MB
    short* S    = (short*)(w + 32 * MB);    // [NTOT,512] bf16 32MB
    float* h    = (float*)(w + 32 * MB);    // [NTOT,128] 16MB (over dead S)
    float* T1   = (float*)(w + 48 * MB);    // [NTOT,256] 32MB
    short* P    = (short*)(w + 64 * MB);    // [NTOT,512] bf16 32MB
    float* tgc2 = (float*)(w + 48 * MB);    // [B,256,128] 8MB
    float* xd2  = (float*)(w + 56 * MB);    // [B,256,128] 8MB
    float* s2   = (float*)(w + 64 * MB);    // [B,256,128] 8MB
    float* t2   = (float*)(w + 72 * MB);    // [B,256,128] 8MB
    float* adj2 = (float*)(w + 0);          // [B,128,128] 4MB
    float* xp2  = (float*)(w + 4 * MB);     // [B,128,128] 4MB
    float* t3   = (float*)(w + 8 * MB);     // [B,128,128] 4MB
    float* xd3  = (float*)(w + 12 * MB);    // [B,128,128] 4MB
    float* adj1 = (float*)(w + 80 * MB);    // [B,256,256] 16MB
    float* xp1  = (float*)(w + 96 * MB);    // [B,256,128] 8MB
    float* qWe  = (float*)(w + 96 * MB);            // [NTOT,5] 640KB (dead before xp1)
    float* ea5n = (float*)(w + 97 * MB);            // [NTOT,5] 640KB
    char* misc  = w + 104 * MB;
    float* W4     = (float*)(misc + 0x00000);
    float* bias4  = (float*)(misc + 0x40000);
    float* scale  = (float*)(misc + 0x41400);
    float* shift  = (float*)(misc + 0x41600);
    float* dinv1  = (float*)(misc + 0x42000);
    float* dinv2  = (float*)(misc + 0x52000);
    int* deg_src  = (int*)(misc + 0x60000);
    int* deg_dst  = (int*)(misc + 0x80000);
    int* rp_src   = (int*)(misc + 0xA0000);
    int* rp_dst   = (int*)(misc + 0xC0000);
    int* cur_src  = (int*)(misc + 0xE0000);
    int* cur_dst  = (int*)(misc + 0x100000);
    int* eid_src  = (int*)(misc + 0x120000);    // 2MB
    int* eid_dst  = (int*)(misc + 0x320000);    // 2MB
    float* psum   = (float*)(misc + 0x520000);  // [256,128] 128KB
    float* psq    = (float*)(misc + 0x540000);  // [256,128] 128KB

    hipMemsetAsync(deg_src, 0, 2 * NTOT * sizeof(int), stream);

    // 1. BatchNorm affine params
    bn_stats_kernel<<<256, 256, 0, stream>>>(x, psum, psq);
    bn_finalize_kernel<<<1, 128, 0, stream>>>(psum, psq, gamma, beta, scale, shift);

    // 2. Pack fused qkvs weights
    pack_w4_kernel<<<256, 256, 0, stream>>>(Wq, Wk, Wv, Wskip, bq, bk, bv, bskip, W4, bias4);

    // 3. CSR by src and dst
    hist_kernel<<<EDGES / 256, 256, 0, stream>>>(ei, deg_src, deg_dst);
    scan_kernel<<<1, 1024, 0, stream>>>(deg_src, rp_src, cur_src);
    scan_kernel<<<1, 1024, 0, stream>>>(deg_dst, rp_dst, cur_dst);
    scatter_kernel<<<EDGES / 256, 256, 0, stream>>>(ei, cur_src, cur_dst, eid_src, eid_dst);

    // 4. qkvs(bf16) = BN(x) @ [Wq|Wk|Wv|Wskip] + biases
    mgemm<false, true, false, false, true><<<dim3(4, 256, 1), 256, 0, stream>>>(
        x, W4, nullptr, nullptr, 0, bias4, qkvs, scale, shift,
        NTOT, 512, 128, 128, 512, 512, 0, 0, 0);

    // 5. qWe = q @ We^T / sqrt(H)
    qwe_kernel<<<(NTOT * EDIM_) / 256, 256, 0, stream>>>(qkvs, We, qWe);

    // 6. S(bf16) = (Q @ K^T) / sqrt(H) per graph (dense, MFMA)
    bgemm<true, true><<<dim3(4, 4, BGRAPH), 256, 0, stream>>>(
        qkvs + 0, qkvs + 128, S, 0.08838834764831845f,
        NNODE, NNODE, 128, 512, 512, 512,
        (long)NNODE * 512, (long)NNODE * 512, (long)NNODE * NNODE);

    // 7. Fused edge-softmax + normalized-P build (16 lanes/node, LDS rows)
    attn_fuse_kernel<<<NTOT / 16, 256, 0, stream>>>(
        S, ei, eattr, qWe, rp_dst, deg_dst, eid_dst, P, ea5n);

    // 8. agg = P @ V ; h = relu(agg + ea5n@We + skip)
    bgemm<false, false><<<dim3(1, 4, BGRAPH), 256, 0, stream>>>(
        P, qkvs + 256, h, 1.0f,
        NNODE, 128, NNODE, 512, 512, 128,
        (long)NNODE * 512, (long)NNODE * 512, (long)NNODE * 128);
    hassemble_kernel<<<(NTOT * 128) / 256, 256, 0, stream>>>(h, ea5n, We, qkvs);

    // 9. s1 = softmax(h @ W_mlp1 + b_mlp1)
    mgemm<false, false, false, false, false><<<dim3(2, 256, 1), 256, 0, stream>>>(
        h, W_mlp1, nullptr, nullptr, 0, b_mlp1, s1, nullptr, nullptr,
        NTOT, K1C, 128, 128, K1C, K1C, 0, 0, 0);
    softmax_kernel<K1C><<<NTOT / 4, 256, 0, stream>>>(s1);

    // 10. T1 = adj @ s1 (sparse)
    spmm_t1_kernel<<<NTOT / 4, 256, 0, stream>>>(s1, ei + EDGES, rp_src, deg_src, eid_src, T1);

    // 11. adj1 = s1^T T1 ; xp1 = s1^T h
    mgemm<true, false, false, false, false><<<dim3(2, 2, BGRAPH), 256, 0, stream>>>(
        s1, T1, nullptr, nullptr, 0, nullptr, adj1, nullptr, nullptr,
        K1C, K1C, NNODE, K1C, K1C, K1C,
        (long)NNODE * K1C, (long)NNODE * K1C, (long)K1C * K1C);
    mgemm<true, false, false, false, false><<<dim3(1, 2, BGRAPH), 256, 0, stream>>>(
        s1, h, nullptr, nullptr, 0, nullptr, xp1, nullptr, nullptr,
        K1C, 128, NNODE, K1C, 128, 128,
        (long)NNODE * K1C, (long)NNODE * 128, (long)K1C * 128);

    // 12. Normalize adj1
    dinv_kernel<K1C><<<(BGRAPH * K1C) / 4, 256, 0, stream>>>(adj1, dinv1);
    scale_adj_kernel<K1C><<<(BGRAPH * K1C * K1C) / 256, 256, 0, stream>>>(adj1, dinv1);

    // 13. GraphConv2
    mgemm<false, false, false, false, false><<<dim3(1, 2, BGRAPH), 256, 0, stream>>>(
        adj1, xp1, nullptr, nullptr, 0, nullptr, tgc2, nullptr, nullptr,
        K1C, 128, K1C, K1C, 128, 128,
        (long)K1C * K1C, (long)K1C * 128, (long)K1C * 128);
    mgemm<false, false, true, true, false><<<dim3(1, 128, 1), 256, 0, stream>>>(
        tgc2, W2_rel, xp1, W2_root, 128, b2_rel, xd2, nullptr, nullptr,
        BGRAPH * K1C, 128, 256, 128, 128, 128, 0, 0, 0);

    // 14. s2 = softmax(xd2 @ W_mlp2 + b_mlp2)
    mgemm<false, false, false, false, false><<<dim3(1, 128, 1), 256, 0, stream>>>(
        xd2, W_mlp2, nullptr, nullptr, 0, b_mlp2, s2, nullptr, nullptr,
        BGRAPH * K1C, K2C, 128, 128, K2C, K2C, 0, 0, 0);
    softmax_kernel<K2C><<<(BGRAPH * K1C) / 4, 256, 0, stream>>>(s2);

    // 15. Pool2
    mgemm<false, false, false, false, false><<<dim3(1, 2, BGRAPH), 256, 0, stream>>>(
        adj1, s2, nullptr, nullptr, 0, nullptr, t2, nullptr, nullptr,
        K1C, K2C, K1C, K1C, K2C, K2C,
        (long)K1C * K1C, (long)K1C * K2C, (long)K1C * K2C);
    mgemm<true, false, false, false, false><<<dim3(1, 1, BGRAPH), 256, 0, stream>>>(
        s2, t2, nullptr, nullptr, 0, nullptr, adj2, nullptr, nullptr,
        K2C, K2C, K1C, K2C, K2C, K2C,
        (long)K1C * K2C, (long)K1C * K2C, (long)K2C * K2C);
    mgemm<true, false, false, false, false><<<dim3(1, 1, BGRAPH), 256, 0, stream>>>(
        s2, xd2, nullptr, nullptr, 0, nullptr, xp2, nullptr, nullptr,
        K2C, 128, K1C, K2C, 128, 128,
        (long)K1C * K2C, (long)K1C * 128, (long)K2C * 128);

    // 16. Normalize adj2
    dinv_kernel<K2C><<<(BGRAPH * K2C) / 4, 256, 0, stream>>>(adj2, dinv2);
    scale_adj_kernel<K2C><<<(BGRAPH * K2C * K2C) / 256, 256, 0, stream>>>(adj2, dinv2);

    // 17. GraphConv3
    mgemm<false, false, false, false, false><<<dim3(1, 1, BGRAPH), 256, 0, stream>>>(
        adj2, xp2, nullptr, nullptr, 0, nullptr, t3, nullptr, nullptr,
        K2C, 128, K2C, K2C, 128, 128,
        (long)K2C * K2C, (long)K2C * 128, (long)K2C * 128);
    mgemm<false, false, false, true, false><<<dim3(1, 64, 1), 256, 0, stream>>>(
        t3, W3_rel, xp2, W3_root, 128, b3_rel, xd3, nullptr, nullptr,
        BGRAPH * K2C, 128, 256, 128, 128, 128, 0, 0, 0);

    // 18. Readout
    readout_kernel<<<BGRAPH, 128, 0, stream>>>(xd3, W_lin1, b_lin1, W_ro, b_ro, out);

    (void)in_sizes; (void)n_in; (void)out_size; (void)ws_size;
}

// Round 7
// 598.103 us; speedup vs baseline: 1.3398x; 1.1105x over previous
//
#include <hip/hip_runtime.h>
#include <math.h>

// Problem constants
#define BGRAPH 64
#define NNODE  512
#define NTOT   32768        // BGRAPH*NNODE
#define CIN    128
#define HDIM   128
#define EDIM_  5
#define EDGES  524288
#define K1C    256
#define K2C    128

using f32x4 = __attribute__((ext_vector_type(4))) float;
using s16x8 = __attribute__((ext_vector_type(8))) short;

__device__ __forceinline__ short f2bf(float f) {
    union { float f; unsigned u; } v; v.f = f;
    unsigned r = v.u + 0x7fffu + ((v.u >> 16) & 1u);   // RNE
    return (short)(r >> 16);
}
__device__ __forceinline__ float bf2f(short s) {
    union { unsigned u; float f; } v; v.u = ((unsigned)(unsigned short)s) << 16;
    return v.f;
}

// ---------------------------------------------------------------------------
// BatchNorm statistics: 256 blocks, float4 loads, per-block partials
// ---------------------------------------------------------------------------
__global__ __launch_bounds__(256) void bn_stats_kernel(const float* __restrict__ x,
                                                       float* __restrict__ psum,
                                                       float* __restrict__ psq) {
    int tid = threadIdx.x, bid = blockIdx.x;
    long idx0 = (long)bid * 256 + tid;            // float4 index
    float4 s = {0.f, 0.f, 0.f, 0.f}, q = {0.f, 0.f, 0.f, 0.f};
#pragma unroll
    for (int it = 0; it < 16; ++it) {
        float4 v = *(const float4*)(x + (idx0 + (long)it * 65536) * 4);
        s.x += v.x; s.y += v.y; s.z += v.z; s.w += v.w;
        q.x += v.x * v.x; q.y += v.y * v.y; q.z += v.z * v.z; q.w += v.w * v.w;
    }
    __shared__ float ss[128], sq[128];
    if (tid < 128) { ss[tid] = 0.f; sq[tid] = 0.f; }
    __syncthreads();
    int c0 = (tid & 31) * 4;
    atomicAdd(&ss[c0 + 0], s.x); atomicAdd(&ss[c0 + 1], s.y);
    atomicAdd(&ss[c0 + 2], s.z); atomicAdd(&ss[c0 + 3], s.w);
    atomicAdd(&sq[c0 + 0], q.x); atomicAdd(&sq[c0 + 1], q.y);
    atomicAdd(&sq[c0 + 2], q.z); atomicAdd(&sq[c0 + 3], q.w);
    __syncthreads();
    if (tid < 128) {
        psum[bid * 128 + tid] = ss[tid];
        psq[bid * 128 + tid]  = sq[tid];
    }
}

__global__ __launch_bounds__(128) void bn_finalize_kernel(const float* __restrict__ psum,
                                                          const float* __restrict__ psq,
                                                          const float* __restrict__ gamma,
                                                          const float* __restrict__ beta,
                                                          float* __restrict__ scale,
                                                          float* __restrict__ shift) {
    int c = threadIdx.x;
    float s = 0.f, q = 0.f;
    for (int b = 0; b < 256; ++b) { s += psum[b * 128 + c]; q += psq[b * 128 + c]; }
    float mu  = s / (float)NTOT;
    float var = q / (float)NTOT - mu * mu;
    float rstd = rsqrtf(var + 1e-5f);
    float sc = gamma[c] * rstd;
    scale[c] = sc;
    shift[c] = beta[c] - mu * sc;
}

// ---------------------------------------------------------------------------
// Pack Wq|Wk|Wv|Wskip into [128,512] and biases into [512]
// ---------------------------------------------------------------------------
__global__ __launch_bounds__(256) void pack_w4_kernel(const float* __restrict__ Wq, const float* __restrict__ Wk,
                                                      const float* __restrict__ Wv, const float* __restrict__ Ws,
                                                      const float* __restrict__ bq, const float* __restrict__ bk,
                                                      const float* __restrict__ bv, const float* __restrict__ bs,
                                                      float* __restrict__ W4, float* __restrict__ bias4) {
    int i = blockIdx.x * 256 + threadIdx.x;
    if (i < 128 * 512) {
        int k = i / 512, j = i % 512;
        float v;
        if (j < 128)      v = Wq[k * 128 + j];
        else if (j < 256) v = Wk[k * 128 + (j - 128)];
        else if (j < 384) v = Wv[k * 128 + (j - 256)];
        else              v = Ws[k * 128 + (j - 384)];
        W4[i] = v;
    }
    if (i < 512) {
        float v;
        if (i < 128)      v = bq[i];
        else if (i < 256) v = bk[i - 128];
        else if (i < 384) v = bv[i - 256];
        else              v = bs[i - 384];
        bias4[i] = v;
    }
}

// ---------------------------------------------------------------------------
// CSR build: histogram, scan (both arrays in one launch), scatter
// ---------------------------------------------------------------------------
__global__ __launch_bounds__(256) void hist_kernel(const int* __restrict__ ei,
                                                   int* __restrict__ deg_src,
                                                   int* __restrict__ deg_dst) {
    int e = blockIdx.x * 256 + threadIdx.x;
    if (e < EDGES) {
        atomicAdd(&deg_src[ei[e]], 1);
        atomicAdd(&deg_dst[ei[EDGES + e]], 1);
    }
}

__global__ __launch_bounds__(1024) void scan2_kernel(const int* __restrict__ deg_src,
                                                     int* __restrict__ rp_src, int* __restrict__ cur_src,
                                                     const int* __restrict__ deg_dst,
                                                     int* __restrict__ rp_dst, int* __restrict__ cur_dst) {
    const int* deg = blockIdx.x ? deg_dst : deg_src;
    int* rowptr    = blockIdx.x ? rp_dst  : rp_src;
    int* cursor    = blockIdx.x ? cur_dst : cur_src;
    __shared__ int part[1024];
    int tid = threadIdx.x;
    int base = tid * 32;
    int s = 0;
    for (int i = 0; i < 32; ++i) s += deg[base + i];
    part[tid] = s;
    __syncthreads();
    for (int off = 1; off < 1024; off <<= 1) {
        int v = part[tid];
        int add = (tid >= off) ? part[tid - off] : 0;
        __syncthreads();
        part[tid] = v + add;
        __syncthreads();
    }
    int run = (tid == 0) ? 0 : part[tid - 1];
    for (int i = 0; i < 32; ++i) {
        rowptr[base + i] = run;
        cursor[base + i] = run;
        run += deg[base + i];
    }
}

__global__ __launch_bounds__(256) void scatter_kernel(const int* __restrict__ ei,
                                                      int* __restrict__ cur_src, int* __restrict__ cur_dst,
                                                      int* __restrict__ eid_src, int* __restrict__ eid_dst) {
    int e = blockIdx.x * 256 + threadIdx.x;
    if (e < EDGES) {
        int s = ei[e], d = ei[EDGES + e];
        eid_src[atomicAdd(&cur_src[s], 1)] = e;
        eid_dst[atomicAdd(&cur_dst[d], 1)] = e;
    }
}

// ---------------------------------------------------------------------------
// BF16 MFMA GEMM. A/B fp32 in global (converted at staging) unless:
//   AU8: A is uint8 (counts), converted u8->bf16 at staging (exact).
//   BBF16: B is already bf16 (k-major), staged without conversion.
// OBF16: epilogue stores bf16. DUAL: concat-K second source pair.
// ---------------------------------------------------------------------------
template <bool TRANS_A, bool AFFINE, bool RELU, bool DUAL, bool OBF16, bool AU8, bool BBF16>
__global__ __launch_bounds__(256) void mgemm(const void* __restrict__ Av,
                                             const void* __restrict__ Bv,
                                             const void* __restrict__ A2v,
                                             const void* __restrict__ B2v,
                                             int Ksplit,
                                             const float* __restrict__ bias,
                                             void* __restrict__ Cv,
                                             const float* __restrict__ scale,
                                             const float* __restrict__ shift,
                                             int M, int Nc, int K,
                                             int lda, int ldb, int ldc,
                                             long sA, long sB, long sC) {
    __shared__ __align__(16) short As[128 * 40];
    __shared__ __align__(16) short Bs[128 * 40];
    const char* Abase = (const char*)Av + (long)blockIdx.z * sA * (AU8 ? 1 : 4);
    const char* Bbase = (const char*)Bv + (long)blockIdx.z * sB * (BBF16 ? 2 : 4);
    float* C = (float*)Cv + (OBF16 ? 0 : (long)blockIdx.z * sC);
    short* Cs = (short*)Cv + (OBF16 ? (long)blockIdx.z * sC : 0);
    const int m0 = blockIdx.y * 128, n0 = blockIdx.x * 128;
    const int tid = threadIdx.x;
    const int lane16 = tid & 15;
    const int quad = (tid & 63) >> 4;
    const int wrow = (tid >> 6) >> 1, wcol = (tid >> 6) & 1;

    f32x4 acc[4][4] = {};

    for (int k0 = 0; k0 < K; k0 += 32) {
        const char* Au = Abase; const char* Bu = Bbase; int ku = k0;
        if (DUAL && k0 >= Ksplit) { Au = (const char*)A2v; Bu = (const char*)B2v; ku = k0 - Ksplit; }

        // ---- stage A tile (128 m x 32 k) ----
        if (!TRANS_A) {
#pragma unroll
            for (int p = 0; p < 4; ++p) {
                int idx = tid + p * 256;
                int row = idx >> 3, c4 = idx & 7;
                short4 o;
                if (AU8) {
                    unsigned u = *(const unsigned*)((const unsigned char*)Au +
                                                    (long)(m0 + row) * lda + ku + c4 * 4);
                    o = make_short4(f2bf((float)(u & 255u)), f2bf((float)((u >> 8) & 255u)),
                                    f2bf((float)((u >> 16) & 255u)), f2bf((float)((u >> 24) & 255u)));
                } else {
                    float4 v = *(const float4*)((const float*)Au + (long)(m0 + row) * lda + ku + c4 * 4);
                    if (AFFINE) {
                        int k = ku + c4 * 4;
                        v.x = v.x * scale[k] + shift[k];
                        v.y = v.y * scale[k + 1] + shift[k + 1];
                        v.z = v.z * scale[k + 2] + shift[k + 2];
                        v.w = v.w * scale[k + 3] + shift[k + 3];
                    }
                    o = make_short4(f2bf(v.x), f2bf(v.y), f2bf(v.z), f2bf(v.w));
                }
                *(short4*)&As[row * 40 + c4 * 4] = o;
            }
        } else {
            int c4 = tid & 31, g = tid >> 5;
            const float* src = (const float*)Au + (long)(ku + g * 4) * lda + m0 + c4 * 4;
            float4 r0 = *(const float4*)(src);
            float4 r1 = *(const float4*)(src + lda);
            float4 r2 = *(const float4*)(src + 2 * lda);
            float4 r3 = *(const float4*)(src + 3 * lda);
            short* d = &As[(c4 * 4) * 40 + g * 4];
            *(short4*)(d + 0 * 40) = make_short4(f2bf(r0.x), f2bf(r1.x), f2bf(r2.x), f2bf(r3.x));
            *(short4*)(d + 1 * 40) = make_short4(f2bf(r0.y), f2bf(r1.y), f2bf(r2.y), f2bf(r3.y));
            *(short4*)(d + 2 * 40) = make_short4(f2bf(r0.z), f2bf(r1.z), f2bf(r2.z), f2bf(r3.z));
            *(short4*)(d + 3 * 40) = make_short4(f2bf(r0.w), f2bf(r1.w), f2bf(r2.w), f2bf(r3.w));
        }
        // ---- stage B tile (32 k x 128 n), transposed to Bs[n][k] ----
        {
            int c4 = tid & 31, g = tid >> 5;
            if (BBF16) {
                const short* src = (const short*)Bu + (long)(ku + g * 4) * ldb + n0 + c4 * 4;
                short4 r0 = *(const short4*)(src);
                short4 r1 = *(const short4*)(src + ldb);
                short4 r2 = *(const short4*)(src + 2 * ldb);
                short4 r3 = *(const short4*)(src + 3 * ldb);
                short* d = &Bs[(c4 * 4) * 40 + g * 4];
                *(short4*)(d + 0 * 40) = make_short4(r0.x, r1.x, r2.x, r3.x);
                *(short4*)(d + 1 * 40) = make_short4(r0.y, r1.y, r2.y, r3.y);
                *(short4*)(d + 2 * 40) = make_short4(r0.z, r1.z, r2.z, r3.z);
                *(short4*)(d + 3 * 40) = make_short4(r0.w, r1.w, r2.w, r3.w);
            } else {
                const float* src = (const float*)Bu + (long)(ku + g * 4) * ldb + n0 + c4 * 4;
                float4 r0 = *(const float4*)(src);
                float4 r1 = *(const float4*)(src + ldb);
                float4 r2 = *(const float4*)(src + 2 * ldb);
                float4 r3 = *(const float4*)(src + 3 * ldb);
                short* d = &Bs[(c4 * 4) * 40 + g * 4];
                *(short4*)(d + 0 * 40) = make_short4(f2bf(r0.x), f2bf(r1.x), f2bf(r2.x), f2bf(r3.x));
                *(short4*)(d + 1 * 40) = make_short4(f2bf(r0.y), f2bf(r1.y), f2bf(r2.y), f2bf(r3.y));
                *(short4*)(d + 2 * 40) = make_short4(f2bf(r0.z), f2bf(r1.z), f2bf(r2.z), f2bf(r3.z));
                *(short4*)(d + 3 * 40) = make_short4(f2bf(r0.w), f2bf(r1.w), f2bf(r2.w), f2bf(r3.w));
            }
        }
        __syncthreads();

        s16x8 af[4], bf[4];
#pragma unroll
        for (int t = 0; t < 4; ++t) {
            af[t] = *(const s16x8*)&As[(wrow * 64 + t * 16 + lane16) * 40 + quad * 8];
            bf[t] = *(const s16x8*)&Bs[(wcol * 64 + t * 16 + lane16) * 40 + quad * 8];
        }
#pragma unroll
        for (int i = 0; i < 4; ++i)
#pragma unroll
            for (int j = 0; j < 4; ++j)
                acc[i][j] = __builtin_amdgcn_mfma_f32_16x16x32_bf16(af[i], bf[j], acc[i][j], 0, 0, 0);
        __syncthreads();
    }

#pragma unroll
    for (int i = 0; i < 4; ++i) {
        int gm = m0 + wrow * 64 + i * 16 + quad * 4;
#pragma unroll
        for (int j = 0; j < 4; ++j) {
            int gn = n0 + wcol * 64 + j * 16 + lane16;
            float bv = bias ? bias[gn] : 0.f;
#pragma unroll
            for (int r = 0; r < 4; ++r) {
                float val = acc[i][j][r] + bv;
                if (RELU) val = fmaxf(val, 0.f);
                if (OBF16) Cs[(long)(gm + r) * ldc + gn] = f2bf(val);
                else       C[(long)(gm + r) * ldc + gn] = val;
            }
        }
    }
}

// ---------------------------------------------------------------------------
// BF16-input MFMA GEMM (no conversion): C = outscale * (A @ B), batched.
// OBF16: store bf16 C.
// ---------------------------------------------------------------------------
template <bool TRANS_B, bool OBF16>
__global__ __launch_bounds__(256) void bgemm(const short* __restrict__ A,
                                             const short* __restrict__ B,
                                             void* __restrict__ Cv,
                                             float outscale,
                                             int M, int Nc, int K,
                                             int lda, int ldb, int ldc,
                                             long sA, long sB, long sC) {
    __shared__ __align__(16) short As[128 * 40];
    __shared__ __align__(16) short Bs[128 * 40];
    A += (long)blockIdx.z * sA;
    B += (long)blockIdx.z * sB;
    float* C = (float*)Cv + (OBF16 ? 0 : (long)blockIdx.z * sC);
    short* Cs = (short*)Cv + (OBF16 ? (long)blockIdx.z * sC : 0);
    const int m0 = blockIdx.y * 128, n0 = blockIdx.x * 128;
    const int tid = threadIdx.x;
    const int lane16 = tid & 15;
    const int quad = (tid & 63) >> 4;
    const int wrow = (tid >> 6) >> 1, wcol = (tid >> 6) & 1;

    f32x4 acc[4][4] = {};

    for (int k0 = 0; k0 < K; k0 += 32) {
#pragma unroll
        for (int p = 0; p < 2; ++p) {
            int u = tid + p * 256;
            int row = u >> 2, g = u & 3;
            *(s16x8*)&As[row * 40 + g * 8] =
                *(const s16x8*)(A + (long)(m0 + row) * lda + k0 + g * 8);
        }
        if (TRANS_B) {
#pragma unroll
            for (int p = 0; p < 2; ++p) {
                int u = tid + p * 256;
                int row = u >> 2, g = u & 3;
                *(s16x8*)&Bs[row * 40 + g * 8] =
                    *(const s16x8*)(B + (long)(n0 + row) * ldb + k0 + g * 8);
            }
        } else {
            int c4 = tid & 31, g = tid >> 5;
            const short* src = B + (long)(k0 + g * 4) * ldb + n0 + c4 * 4;
            short4 r0 = *(const short4*)(src);
            short4 r1 = *(const short4*)(src + ldb);
            short4 r2 = *(const short4*)(src + 2 * ldb);
            short4 r3 = *(const short4*)(src + 3 * ldb);
            short* d = &Bs[(c4 * 4) * 40 + g * 4];
            *(short4*)(d + 0 * 40) = make_short4(r0.x, r1.x, r2.x, r3.x);
            *(short4*)(d + 1 * 40) = make_short4(r0.y, r1.y, r2.y, r3.y);
            *(short4*)(d + 2 * 40) = make_short4(r0.z, r1.z, r2.z, r3.z);
            *(short4*)(d + 3 * 40) = make_short4(r0.w, r1.w, r2.w, r3.w);
        }
        __syncthreads();

        s16x8 af[4], bf[4];
#pragma unroll
        for (int t = 0; t < 4; ++t) {
            af[t] = *(const s16x8*)&As[(wrow * 64 + t * 16 + lane16) * 40 + quad * 8];
            bf[t] = *(const s16x8*)&Bs[(wcol * 64 + t * 16 + lane16) * 40 + quad * 8];
        }
#pragma unroll
        for (int i = 0; i < 4; ++i)
#pragma unroll
            for (int j = 0; j < 4; ++j)
                acc[i][j] = __builtin_amdgcn_mfma_f32_16x16x32_bf16(af[i], bf[j], acc[i][j], 0, 0, 0);
        __syncthreads();
    }

#pragma unroll
    for (int i = 0; i < 4; ++i) {
        int gm = m0 + wrow * 64 + i * 16 + quad * 4;
#pragma unroll
        for (int j = 0; j < 4; ++j) {
            int gn = n0 + wcol * 64 + j * 16 + lane16;
#pragma unroll
            for (int r = 0; r < 4; ++r) {
                float val = acc[i][j][r] * outscale;
                if (OBF16) Cs[(long)(gm + r) * ldc + gn] = f2bf(val);
                else       C[(long)(gm + r) * ldc + gn] = val;
            }
        }
    }
}

// ---------------------------------------------------------------------------
// qWe[node][d] = (q[node,:] . We[d,:]) / sqrt(H) — thread per (node,d)
// ---------------------------------------------------------------------------
__global__ __launch_bounds__(256) void qwe_kernel(const short* __restrict__ qkvs,
                                                  const float* __restrict__ We,
                                                  float* __restrict__ qWe) {
    __shared__ float sWe[EDIM_ * 128];
    for (int i = threadIdx.x; i < EDIM_ * 128; i += 256) sWe[i] = We[i];
    __syncthreads();
    int i = blockIdx.x * 256 + threadIdx.x;        // < NTOT*5
    int node = i / 5, d = i - node * 5;
    const s16x8* row = (const s16x8*)(qkvs + (long)node * 512);
    float acc = 0.f;
#pragma unroll
    for (int g = 0; g < 16; ++g) {
        s16x8 v = row[g];
#pragma unroll
        for (int j = 0; j < 8; ++j) acc += bf2f(v[j]) * sWe[d * 128 + g * 8 + j];
    }
    qWe[i] = acc * 0.08838834764831845f;           // 1/sqrt(128)
}

// ---------------------------------------------------------------------------
// Fused edge-softmax + P-row build. 16 lanes per dst node, 16 nodes/block.
// ---------------------------------------------------------------------------
__global__ __launch_bounds__(256) void attn_fuse_kernel(const short* __restrict__ S,
                                                        const int* __restrict__ ei,
                                                        const float* __restrict__ eattr,
                                                        const float* __restrict__ qWe,
                                                        const int* __restrict__ rp_dst,
                                                        const int* __restrict__ deg_dst,
                                                        const int* __restrict__ eid_dst,
                                                        short* __restrict__ P,
                                                        float* __restrict__ ea5n) {
    __shared__ float rows[16][512];                // 32 KB
    int g = threadIdx.x >> 4;
    int lane = threadIdx.x & 15;
    int node = blockIdx.x * 16 + g;
    float* row = rows[g];
    for (int i = lane; i < 512; i += 16) row[i] = 0.f;
    float qw[EDIM_];
#pragma unroll
    for (int d = 0; d < EDIM_; ++d) qw[d] = qWe[node * EDIM_ + d];
    int start = rp_dst[node], cnt = deg_dst[node];
    const short* Srow = S + (long)node * 512;
    float lsum = 0.f, a5[EDIM_] = {};
    for (int t = lane; t < cnt; t += 16) {
        int e = eid_dst[start + t];
        int src = ei[e] & 511;
        float lg = bf2f(Srow[src]);
        float ea[EDIM_];
#pragma unroll
        for (int d = 0; d < EDIM_; ++d) { ea[d] = eattr[e * EDIM_ + d]; lg += ea[d] * qw[d]; }
        float wv = expf(lg);                       // logits are O(1): no max-pass needed
        lsum += wv;
#pragma unroll
        for (int d = 0; d < EDIM_; ++d) a5[d] += wv * ea[d];
        atomicAdd(&row[src], wv);                  // LDS atomic (duplicate-src safe)
    }
#pragma unroll
    for (int off = 8; off; off >>= 1) {
        lsum += __shfl_xor(lsum, off);
#pragma unroll
        for (int d = 0; d < EDIM_; ++d) a5[d] += __shfl_xor(a5[d], off);
    }
    float inv = (lsum > 0.f) ? 1.f / lsum : 0.f;
    if (lane < EDIM_) {
        float v = lane == 0 ? a5[0] : lane == 1 ? a5[1] : lane == 2 ? a5[2]
                : lane == 3 ? a5[3] : a5[4];
        ea5n[node * EDIM_ + lane] = v * inv;
    }
    unsigned* Pr = (unsigned*)(P + (long)node * 512);
    for (int i = lane; i < 256; i += 16) {
        float v0 = row[2 * i] * inv, v1 = row[2 * i + 1] * inv;
        unsigned pack = (unsigned)(unsigned short)f2bf(v0)
                      | ((unsigned)(unsigned short)f2bf(v1) << 16);
        Pr[i] = pack;
    }
}

// ---------------------------------------------------------------------------
// Dense adjacency count build: Adense[src][dst] = #edges (uint8), by src-CSR.
// 16 lanes per src node, LDS int row; zero global atomics.
// ---------------------------------------------------------------------------
__global__ __launch_bounds__(256) void adense_kernel(const int* __restrict__ ei,
                                                     const int* __restrict__ rp_src,
                                                     const int* __restrict__ deg_src,
                                                     const int* __restrict__ eid_src,
                                                     unsigned char* __restrict__ Adense) {
    __shared__ int rows[16][512];                  // 32 KB
    int g = threadIdx.x >> 4;
    int lane = threadIdx.x & 15;
    int node = blockIdx.x * 16 + g;
    int* row = rows[g];
    for (int i = lane; i < 512; i += 16) row[i] = 0;
    int start = rp_src[node], cnt = deg_src[node];
    for (int t = lane; t < cnt; t += 16) {
        int e = eid_src[start + t];
        int dst = ei[EDGES + e] & 511;
        atomicAdd(&row[dst], 1);
    }
    unsigned* Ar = (unsigned*)(Adense + (long)node * 512);
    for (int i = lane; i < 128; i += 16) {
        unsigned p = (unsigned)row[4 * i]
                   | ((unsigned)row[4 * i + 1] << 8)
                   | ((unsigned)row[4 * i + 2] << 16)
                   | ((unsigned)row[4 * i + 3] << 24);
        Ar[i] = p;
    }
}

// ---------------------------------------------------------------------------
// h = relu(agg + ea5n @ We + skip)   (in place over agg)
// ---------------------------------------------------------------------------
__global__ __launch_bounds__(256) void hassemble_kernel(float* __restrict__ h,
                                                        const float* __restrict__ ea5n,
                                                        const float* __restrict__ We,
                                                        const short* __restrict__ qkvs) {
    long i = (long)blockIdx.x * 256 + threadIdx.x;   // over NTOT*128
    int node = (int)(i >> 7);
    int c = (int)(i & 127);
    float ecorr = 0.f;
#pragma unroll
    for (int d = 0; d < EDIM_; ++d) ecorr += ea5n[node * EDIM_ + d] * We[d * 128 + c];
    float v = h[i] + ecorr + bf2f(qkvs[(long)node * 512 + 384 + c]);
    h[i] = fmaxf(v, 0.f);
}

// ---------------------------------------------------------------------------
// Row-wise softmax over NC columns, wave per row
// ---------------------------------------------------------------------------
template <int NC>
__global__ __launch_bounds__(256) void softmax_kernel(float* __restrict__ s) {
    int wave = threadIdx.x >> 6;
    int lane = threadIdx.x & 63;
    int row = blockIdx.x * 4 + wave;
    float* p = s + (long)row * NC;
    constexpr int PER = NC / 64;
    float v[PER];
    float mx = -INFINITY;
#pragma unroll
    for (int j = 0; j < PER; ++j) { v[j] = p[lane + j * 64]; mx = fmaxf(mx, v[j]); }
#pragma unroll
    for (int off = 32; off; off >>= 1) mx = fmaxf(mx, __shfl_xor(mx, off));
    float sm = 0.f;
#pragma unroll
    for (int j = 0; j < PER; ++j) { v[j] = expf(v[j] - mx); sm += v[j]; }
#pragma unroll
    for (int off = 32; off; off >>= 1) sm += __shfl_xor(sm, off);
    float inv = 1.f / sm;
#pragma unroll
    for (int j = 0; j < PER; ++j) p[lane + j * 64] = v[j] * inv;
}

// ---------------------------------------------------------------------------
// Pooled-adj normalization
// ---------------------------------------------------------------------------
template <int KC>
__global__ __launch_bounds__(256) void dinv_kernel(const float* __restrict__ adj,
                                                   float* __restrict__ dinv) {
    int wave = threadIdx.x >> 6;
    int lane = threadIdx.x & 63;
    int row = blockIdx.x * 4 + wave;
    int b = row / KC, r = row % KC;
    const float* p = adj + (long)b * KC * KC + (long)r * KC;
    float s = 0.f;
    for (int j = lane; j < KC; j += 64)
        if (j != r) s += p[j];
#pragma unroll
    for (int off = 32; off; off >>= 1) s += __shfl_xor(s, off);
    if (lane == 0) dinv[row] = 1.f / (sqrtf(s) + 1e-15f);
}

template <int KC>
__global__ __launch_bounds__(256) void scale_adj_kernel(float* __restrict__ adj,
                                                        const float* __restrict__ dinv) {
    long i = (long)blockIdx.x * 256 + threadIdx.x;
    int c = (int)(i % KC);
    long t = i / KC;
    int r = (int)(t % KC);
    int b = (int)(t / KC);
    float v = adj[i];
    v = (r == c) ? 0.f : v * dinv[b * KC + r] * dinv[b * KC + c];
    adj[i] = v;
}

// ---------------------------------------------------------------------------
// Readout
// ---------------------------------------------------------------------------
__global__ __launch_bounds__(128) void readout_kernel(const float* __restrict__ xd3,
                                                      const float* __restrict__ W_lin1,
                                                      const float* __restrict__ b_lin1,
                                                      const float* __restrict__ W_ro,
                                                      const float* __restrict__ b_ro,
                                                      float* __restrict__ out) {
    int b = blockIdx.x, t = threadIdx.x;
    __shared__ float g[128], g2[128], wred[2];
    const float* X = xd3 + (long)b * K2C * 128;
    float s = 0.f;
    for (int r = 0; r < K2C; ++r) s += X[r * 128 + t];
    g[t] = s * (1.f / (float)K2C);
    __syncthreads();
    float u = b_lin1[t];
    for (int k = 0; k < 128; ++k) u += g[k] * W_lin1[k * 128 + t];
    g2[t] = fmaxf(u, 0.f);
    __syncthreads();
    float p = g2[t] * W_ro[t];
#pragma unroll
    for (int off = 32; off; off >>= 1) p += __shfl_xor(p, off);
    if ((t & 63) == 0) wred[t >> 6] = p;
    __syncthreads();
    if (t == 0) {
        float tot = wred[0] + wred[1] + b_ro[0];
        out[b] = 1.f / (1.f + expf(-tot));
    }
}

// ---------------------------------------------------------------------------
extern "C" void kernel_launch(void* const* d_in, const int* in_sizes, int n_in,
                              void* d_out, int out_size, void* d_ws, size_t ws_size,
                              hipStream_t stream) {
    const float* x      = (const float*)d_in[0];
    const int*   ei     = (const int*)d_in[1];
    const float* eattr  = (const float*)d_in[2];
    const float* gamma  = (const float*)d_in[4];
    const float* beta   = (const float*)d_in[5];
    const float* Wq     = (const float*)d_in[6];
    const float* bq     = (const float*)d_in[7];
    const float* Wk     = (const float*)d_in[8];
    const float* bk     = (const float*)d_in[9];
    const float* Wv     = (const float*)d_in[10];
    const float* bv     = (const float*)d_in[11];
    const float* We     = (const float*)d_in[12];
    const float* Wskip  = (const float*)d_in[13];
    const float* bskip  = (const float*)d_in[14];
    const float* W_mlp1 = (const float*)d_in[15];
    const float* b_mlp1 = (const float*)d_in[16];
    const float* W2_rel = (const float*)d_in[17];
    const float* b2_rel = (const float*)d_in[18];
    const float* W2_root= (const float*)d_in[19];
    const float* W_mlp2 = (const float*)d_in[20];
    const float* b_mlp2 = (const float*)d_in[21];
    const float* W3_rel = (const float*)d_in[22];
    const float* b3_rel = (const float*)d_in[23];
    const float* W3_root= (const float*)d_in[24];
    const float* W_lin1 = (const float*)d_in[25];
    const float* b_lin1 = (const float*)d_in[26];
    const float* W_ro   = (const float*)d_in[27];
    const float* b_ro   = (const float*)d_in[28];
    float* out = (float*)d_out;

    char* w = (char*)d_ws;
    const size_t MB = 1ull << 20;
    // Workspace plan (peak 110 MB), lifetime-aliased:
    //  [0,32)   qkvs bf16 (4-8) → s1 fp32 (9-11) → adj2/xp2/t3/xd3 (15+)
    //  [32,64)  S bf16 (6-7) → h fp32 [32,48) (8-11) ; T1 bf16 [48,64) (10-11)
    //           → tgc2[48,56) xd2[56,64) (13+)
    //  [64,96)  P bf16 (7-8) → Adense u8 [64,80) (8.5-10) → s2[64,72) t2[72,80) (14+)
    //  [80,96)  adj1 (11-15)
    //  [96,104) qWe/ea5n (5-8) → xp1 (11-15)
    //  [104,110) misc
    short* qkvs = (short*)(w + 0);          // [NTOT,512] bf16 32MB
    float* s1   = (float*)(w + 0);          // [NTOT,256] 32MB
    short* S    = (short*)(w + 32 * MB);    // [NTOT,512] bf16 32MB
    float* h    = (float*)(w + 32 * MB);    // [NTOT,128] 16MB (over dead S)
    short* T1s  = (short*)(w + 48 * MB);    // [NTOT,256] bf16 16MB
    short* P    = (short*)(w + 64 * MB);    // [NTOT,512] bf16 32MB
    unsigned char* Aden = (unsigned char*)(w + 64 * MB);  // [NTOT,512] u8 16MB (over dead P)
    float* tgc2 = (float*)(w + 48 * MB);    // [B,256,128] 8MB
    float* xd2  = (float*)(w + 56 * MB);    // [B,256,128] 8MB
    float* s2   = (float*)(w + 64 * MB);    // [B,256,128] 8MB
    float* t2   = (float*)(w + 72 * MB);    // [B,256,128] 8MB
    float* adj2 = (float*)(w + 0);          // [B,128,128] 4MB
    float* xp2  = (float*)(w + 4 * MB);     // [B,128,128] 4MB
    float* t3   = (float*)(w + 8 * MB);     // [B,128,128] 4MB
    float* xd3  = (float*)(w + 12 * MB);    // [B,128,128] 4MB
    float* adj1 = (float*)(w + 80 * MB);    // [B,256,256] 16MB
    float* xp1  = (float*)(w + 96 * MB);    // [B,256,128] 8MB
    float* qWe  = (float*)(w + 96 * MB);    // [NTOT,5] 640KB (dead before xp1)
    float* ea5n = (float*)(w + 97 * MB);    // [NTOT,5] 640KB
    char* misc  = w + 104 * MB;
    float* W4     = (float*)(misc + 0x00000);
    float* bias4  = (float*)(misc + 0x40000);
    float* scale  = (float*)(misc + 0x41400);
    float* shift  = (float*)(misc + 0x41600);
    float* dinv1  = (float*)(misc + 0x42000);
    float* dinv2  = (float*)(misc + 0x52000);
    int* deg_src  = (int*)(misc + 0x60000);
    int* deg_dst  = (int*)(misc + 0x80000);
    int* rp_src   = (int*)(misc + 0xA0000);
    int* rp_dst   = (int*)(misc + 0xC0000);
    int* cur_src  = (int*)(misc + 0xE0000);
    int* cur_dst  = (int*)(misc + 0x100000);
    int* eid_src  = (int*)(misc + 0x120000);    // 2MB
    int* eid_dst  = (int*)(misc + 0x320000);    // 2MB
    float* psum   = (float*)(misc + 0x520000);  // [256,128] 128KB
    float* psq    = (float*)(misc + 0x540000);  // [256,128] 128KB

    hipMemsetAsync(deg_src, 0, 2 * NTOT * sizeof(int), stream);

    // 1. BatchNorm affine params
    bn_stats_kernel<<<256, 256, 0, stream>>>(x, psum, psq);
    bn_finalize_kernel<<<1, 128, 0, stream>>>(psum, psq, gamma, beta, scale, shift);

    // 2. Pack fused qkvs weights
    pack_w4_kernel<<<256, 256, 0, stream>>>(Wq, Wk, Wv, Wskip, bq, bk, bv, bskip, W4, bias4);

    // 3. CSR by src and dst (single scan launch, 2 blocks)
    hist_kernel<<<EDGES / 256, 256, 0, stream>>>(ei, deg_src, deg_dst);
    scan2_kernel<<<2, 1024, 0, stream>>>(deg_src, rp_src, cur_src, deg_dst, rp_dst, cur_dst);
    scatter_kernel<<<EDGES / 256, 256, 0, stream>>>(ei, cur_src, cur_dst, eid_src, eid_dst);

    // 4. qkvs(bf16) = BN(x) @ [Wq|Wk|Wv|Wskip] + biases
    mgemm<false, true, false, false, true, false, false><<<dim3(4, 256, 1), 256, 0, stream>>>(
        x, W4, nullptr, nullptr, 0, bias4, qkvs, scale, shift,
        NTOT, 512, 128, 128, 512, 512, 0, 0, 0);

    // 5. qWe = q @ We^T / sqrt(H)
    qwe_kernel<<<(NTOT * EDIM_) / 256, 256, 0, stream>>>(qkvs, We, qWe);

    // 6. S(bf16) = (Q @ K^T) / sqrt(H) per graph (dense, MFMA)
    bgemm<true, true><<<dim3(4, 4, BGRAPH), 256, 0, stream>>>(
        qkvs + 0, qkvs + 128, S, 0.08838834764831845f,
        NNODE, NNODE, 128, 512, 512, 512,
        (long)NNODE * 512, (long)NNODE * 512, (long)NNODE * NNODE);

    // 7. Fused edge-softmax + normalized-P build
    attn_fuse_kernel<<<NTOT / 16, 256, 0, stream>>>(
        S, ei, eattr, qWe, rp_dst, deg_dst, eid_dst, P, ea5n);

    // 8. agg = P @ V ; build Adense (over dead P region after PV) ; assemble h
    bgemm<false, false><<<dim3(1, 4, BGRAPH), 256, 0, stream>>>(
        P, qkvs + 256, h, 1.0f,
        NNODE, 128, NNODE, 512, 512, 128,
        (long)NNODE * 512, (long)NNODE * 512, (long)NNODE * 128);
    adense_kernel<<<NTOT / 16, 256, 0, stream>>>(ei, rp_src, deg_src, eid_src, Aden);
    hassemble_kernel<<<(NTOT * 128) / 256, 256, 0, stream>>>(h, ea5n, We, qkvs);

    // 9. s1 = softmax(h @ W_mlp1 + b_mlp1)
    mgemm<false, false, false, false, false, false, false><<<dim3(2, 256, 1), 256, 0, stream>>>(
        h, W_mlp1, nullptr, nullptr, 0, b_mlp1, s1, nullptr, nullptr,
        NTOT, K1C, 128, 128, K1C, K1C, 0, 0, 0);
    softmax_kernel<K1C><<<NTOT / 4, 256, 0, stream>>>(s1);

    // 10. T1(bf16) = Adense(u8) @ s1 per graph — replaces the gather SpMM
    mgemm<false, false, false, false, true, true, false><<<dim3(2, 4, BGRAPH), 256, 0, stream>>>(
        Aden, s1, nullptr, nullptr, 0, nullptr, T1s, nullptr, nullptr,
        NNODE, K1C, NNODE, NNODE, K1C, K1C,
        (long)NNODE * NNODE, (long)NNODE * K1C, (long)NNODE * K1C);

    // 11. adj1 = s1^T T1 (B bf16) ; xp1 = s1^T h
    mgemm<true, false, false, false, false, false, true><<<dim3(2, 2, BGRAPH), 256, 0, stream>>>(
        s1, T1s, nullptr, nullptr, 0, nullptr, adj1, nullptr, nullptr,
        K1C, K1C, NNODE, K1C, K1C, K1C,
        (long)NNODE * K1C, (long)NNODE * K1C, (long)K1C * K1C);
    mgemm<true, false, false, false, false, false, false><<<dim3(1, 2, BGRAPH), 256, 0, stream>>>(
        s1, h, nullptr, nullptr, 0, nullptr, xp1, nullptr, nullptr,
        K1C, 128, NNODE, K1C, 128, 128,
        (long)NNODE * K1C, (long)NNODE * 128, (long)K1C * 128);

    // 12. Normalize adj1
    dinv_kernel<K1C><<<(BGRAPH * K1C) / 4, 256, 0, stream>>>(adj1, dinv1);
    scale_adj_kernel<K1C><<<(BGRAPH * K1C * K1C) / 256, 256, 0, stream>>>(adj1, dinv1);

    // 13. GraphConv2
    mgemm<false, false, false, false, false, false, false><<<dim3(1, 2, BGRAPH), 256, 0, stream>>>(
        adj1, xp1, nullptr, nullptr, 0, nullptr, tgc2, nullptr, nullptr,
        K1C, 128, K1C, K1C, 128, 128,
        (long)K1C * K1C, (long)K1C * 128, (long)K1C * 128);
    mgemm<false, false, true, true, false, false, false><<<dim3(1, 128, 1), 256, 0, stream>>>(
        tgc2, W2_rel, xp1, W2_root, 128, b2_rel, xd2, nullptr, nullptr,
        BGRAPH * K1C, 128, 256, 128, 128, 128, 0, 0, 0);

    // 14. s2 = softmax(xd2 @ W_mlp2 + b_mlp2)
    mgemm<false, false, false, false, false, false, false><<<dim3(1, 128, 1), 256, 0, stream>>>(
        xd2, W_mlp2, nullptr, nullptr, 0, b_mlp2, s2, nullptr, nullptr,
        BGRAPH * K1C, K2C, 128, 128, K2C, K2C, 0, 0, 0);
    softmax_kernel<K2C><<<(BGRAPH * K1C) / 4, 256, 0, stream>>>(s2);

    // 15. Pool2
    mgemm<false, false, false, false, false, false, false><<<dim3(1, 2, BGRAPH), 256, 0, stream>>>(
        adj1, s2, nullptr, nullptr, 0, nullptr, t2, nullptr, nullptr,
        K1C, K2C, K1C, K1C, K2C, K2C,
        (long)K1C * K1C, (long)K1C * K2C, (long)K1C * K2C);
    mgemm<true, false, false, false, false, false, false><<<dim3(1, 1, BGRAPH), 256, 0, stream>>>(
        s2, t2, nullptr, nullptr, 0, nullptr, adj2, nullptr, nullptr,
        K2C, K2C, K1C, K2C, K2C, K2C,
        (long)K1C * K2C, (long)K1C * K2C, (long)K2C * K2C);
    mgemm<true, false, false, false, false, false, false><<<dim3(1, 1, BGRAPH), 256, 0, stream>>>(
        s2, xd2, nullptr, nullptr, 0, nullptr, xp2, nullptr, nullptr,
        K2C, 128, K1C, K2C, 128, 128,
        (long)K1C * K2C, (long)K1C * 128, (long)K2C * 128);

    // 16. Normalize adj2
    dinv_kernel<K2C><<<(BGRAPH * K2C) / 4, 256, 0, stream>>>(adj2, dinv2);
    scale_adj_kernel<K2C><<<(BGRAPH * K2C * K2C) / 256, 256, 0, stream>>>(adj2, dinv2);

    // 17. GraphConv3
    mgemm<false, false, false, false, false, false, false><<<dim3(1, 1, BGRAPH), 256, 0, stream>>>(
        adj2, xp2, nullptr, nullptr, 0, nullptr, t3, nullptr, nullptr,
        K2C, 128, K2C, K2C, 128, 128,
        (long)K2C * K2C, (long)K2C * 128, (long)K2C * 128);
    mgemm<false, false, false, true, false, false, false><<<dim3(1, 64, 1), 256, 0, stream>>>(
        t3, W3_rel, xp2, W3_root, 128, b3_rel, xd3, nullptr, nullptr,
        BGRAPH * K2C, 128, 256, 128, 128, 128, 0, 0, 0);

    // 18. Readout
    readout_kernel<<<BGRAPH, 128, 0, stream>>>(xd3, W_lin1, b_lin1, W_ro, b_ro, out);

    (void)in_sizes; (void)n_in; (void)out_size; (void)ws_size;
}

// Round 8
// 572.002 us; speedup vs baseline: 1.4009x; 1.0456x over previous
//
#include <hip/hip_runtime.h>
#include <math.h>

// Problem constants
#define BGRAPH 64
#define NNODE  512
#define NTOT   32768        // BGRAPH*NNODE
#define CIN    128
#define HDIM   128
#define EDIM_  5
#define EDGES  524288
#define K1C    256
#define K2C    128

using f32x4 = __attribute__((ext_vector_type(4))) float;
using s16x8 = __attribute__((ext_vector_type(8))) short;

__device__ __forceinline__ short f2bf(float f) {
    union { float f; unsigned u; } v; v.f = f;
    unsigned r = v.u + 0x7fffu + ((v.u >> 16) & 1u);   // RNE
    return (short)(r >> 16);
}
__device__ __forceinline__ float bf2f(short s) {
    union { unsigned u; float f; } v; v.u = ((unsigned)(unsigned short)s) << 16;
    return v.f;
}

// ---------------------------------------------------------------------------
// BatchNorm statistics: 256 blocks, float4 loads, per-block partials
// ---------------------------------------------------------------------------
__global__ __launch_bounds__(256) void bn_stats_kernel(const float* __restrict__ x,
                                                       float* __restrict__ psum,
                                                       float* __restrict__ psq) {
    int tid = threadIdx.x, bid = blockIdx.x;
    long idx0 = (long)bid * 256 + tid;
    float4 s = {0.f, 0.f, 0.f, 0.f}, q = {0.f, 0.f, 0.f, 0.f};
#pragma unroll
    for (int it = 0; it < 16; ++it) {
        float4 v = *(const float4*)(x + (idx0 + (long)it * 65536) * 4);
        s.x += v.x; s.y += v.y; s.z += v.z; s.w += v.w;
        q.x += v.x * v.x; q.y += v.y * v.y; q.z += v.z * v.z; q.w += v.w * v.w;
    }
    __shared__ float ss[128], sq[128];
    if (tid < 128) { ss[tid] = 0.f; sq[tid] = 0.f; }
    __syncthreads();
    int c0 = (tid & 31) * 4;
    atomicAdd(&ss[c0 + 0], s.x); atomicAdd(&ss[c0 + 1], s.y);
    atomicAdd(&ss[c0 + 2], s.z); atomicAdd(&ss[c0 + 3], s.w);
    atomicAdd(&sq[c0 + 0], q.x); atomicAdd(&sq[c0 + 1], q.y);
    atomicAdd(&sq[c0 + 2], q.z); atomicAdd(&sq[c0 + 3], q.w);
    __syncthreads();
    if (tid < 128) {
        psum[bid * 128 + tid] = ss[tid];
        psq[bid * 128 + tid]  = sq[tid];
    }
}

__global__ __launch_bounds__(128) void bn_finalize_kernel(const float* __restrict__ psum,
                                                          const float* __restrict__ psq,
                                                          const float* __restrict__ gamma,
                                                          const float* __restrict__ beta,
                                                          float* __restrict__ scale,
                                                          float* __restrict__ shift) {
    int c = threadIdx.x;
    float s = 0.f, q = 0.f;
    for (int b = 0; b < 256; ++b) { s += psum[b * 128 + c]; q += psq[b * 128 + c]; }
    float mu  = s / (float)NTOT;
    float var = q / (float)NTOT - mu * mu;
    float rstd = rsqrtf(var + 1e-5f);
    float sc = gamma[c] * rstd;
    scale[c] = sc;
    shift[c] = beta[c] - mu * sc;
}

// ---------------------------------------------------------------------------
// Pack Wq|Wk|Wv|Wskip into [128,512] and biases into [512]
// ---------------------------------------------------------------------------
__global__ __launch_bounds__(256) void pack_w4_kernel(const float* __restrict__ Wq, const float* __restrict__ Wk,
                                                      const float* __restrict__ Wv, const float* __restrict__ Ws,
                                                      const float* __restrict__ bq, const float* __restrict__ bk,
                                                      const float* __restrict__ bv, const float* __restrict__ bs,
                                                      float* __restrict__ W4, float* __restrict__ bias4) {
    int i = blockIdx.x * 256 + threadIdx.x;
    if (i < 128 * 512) {
        int k = i / 512, j = i % 512;
        float v;
        if (j < 128)      v = Wq[k * 128 + j];
        else if (j < 256) v = Wk[k * 128 + (j - 128)];
        else if (j < 384) v = Wv[k * 128 + (j - 256)];
        else              v = Ws[k * 128 + (j - 384)];
        W4[i] = v;
    }
    if (i < 512) {
        float v;
        if (i < 128)      v = bq[i];
        else if (i < 256) v = bk[i - 128];
        else if (i < 384) v = bv[i - 256];
        else              v = bs[i - 384];
        bias4[i] = v;
    }
}

// ---------------------------------------------------------------------------
// CSR build: histogram, scan (both arrays in one launch), scatter
// ---------------------------------------------------------------------------
__global__ __launch_bounds__(256) void hist_kernel(const int* __restrict__ ei,
                                                   int* __restrict__ deg_src,
                                                   int* __restrict__ deg_dst) {
    int e = blockIdx.x * 256 + threadIdx.x;
    if (e < EDGES) {
        atomicAdd(&deg_src[ei[e]], 1);
        atomicAdd(&deg_dst[ei[EDGES + e]], 1);
    }
}

__global__ __launch_bounds__(1024) void scan2_kernel(const int* __restrict__ deg_src,
                                                     int* __restrict__ rp_src, int* __restrict__ cur_src,
                                                     const int* __restrict__ deg_dst,
                                                     int* __restrict__ rp_dst, int* __restrict__ cur_dst) {
    const int* deg = blockIdx.x ? deg_dst : deg_src;
    int* rowptr    = blockIdx.x ? rp_dst  : rp_src;
    int* cursor    = blockIdx.x ? cur_dst : cur_src;
    __shared__ int part[1024];
    int tid = threadIdx.x;
    int base = tid * 32;
    int s = 0;
    for (int i = 0; i < 32; ++i) s += deg[base + i];
    part[tid] = s;
    __syncthreads();
    for (int off = 1; off < 1024; off <<= 1) {
        int v = part[tid];
        int add = (tid >= off) ? part[tid - off] : 0;
        __syncthreads();
        part[tid] = v + add;
        __syncthreads();
    }
    int run = (tid == 0) ? 0 : part[tid - 1];
    for (int i = 0; i < 32; ++i) {
        rowptr[base + i] = run;
        cursor[base + i] = run;
        run += deg[base + i];
    }
}

__global__ __launch_bounds__(256) void scatter_kernel(const int* __restrict__ ei,
                                                      int* __restrict__ cur_src, int* __restrict__ cur_dst,
                                                      int* __restrict__ eid_src, int* __restrict__ eid_dst) {
    int e = blockIdx.x * 256 + threadIdx.x;
    if (e < EDGES) {
        int s = ei[e], d = ei[EDGES + e];
        eid_src[atomicAdd(&cur_src[s], 1)] = e;
        eid_dst[atomicAdd(&cur_dst[d], 1)] = e;
    }
}

// ---------------------------------------------------------------------------
// BF16 MFMA GEMM, tile TILE x TILE (128 or 64), BK=32.
//   AU8: A uint8 counts (exact). ATRBF16: TRANS_A with bf16 A.
//   BBF16: B already bf16. OBF16: bf16 output. DUAL: concat-K second source.
// ---------------------------------------------------------------------------
template <int TILE, bool TRANS_A, bool AFFINE, bool RELU, bool DUAL,
          bool OBF16, bool AU8, bool BBF16, bool ATRBF16>
__global__ __launch_bounds__(256) void mgemm(const void* __restrict__ Av,
                                             const void* __restrict__ Bv,
                                             const void* __restrict__ A2v,
                                             const void* __restrict__ B2v,
                                             int Ksplit,
                                             const float* __restrict__ bias,
                                             void* __restrict__ Cv,
                                             const float* __restrict__ scale,
                                             const float* __restrict__ shift,
                                             int M, int Nc, int K,
                                             int lda, int ldb, int ldc,
                                             long sA, long sB, long sC) {
    __shared__ __align__(16) short As[TILE * 40];
    __shared__ __align__(16) short Bs[TILE * 40];
    constexpr int ASZ = AU8 ? 1 : (ATRBF16 ? 2 : 4);
    constexpr int BSZ = BBF16 ? 2 : 4;
    const char* Abase = (const char*)Av + (long)blockIdx.z * sA * ASZ;
    const char* Bbase = (const char*)Bv + (long)blockIdx.z * sB * BSZ;
    float* C = (float*)Cv + (OBF16 ? 0 : (long)blockIdx.z * sC);
    short* Cs = (short*)Cv + (OBF16 ? (long)blockIdx.z * sC : 0);
    const int m0 = blockIdx.y * TILE, n0 = blockIdx.x * TILE;
    const int tid = threadIdx.x;
    const int lane16 = tid & 15;
    const int quad = (tid & 63) >> 4;
    const int wrow = (tid >> 6) >> 1, wcol = (tid >> 6) & 1;
    constexpr int WT = TILE / 32;                 // 16x16 MFMA tiles per wave dim

    f32x4 acc[WT][WT] = {};

    for (int k0 = 0; k0 < K; k0 += 32) {
        const char* Au = Abase; const char* Bu = Bbase; int ku = k0;
        if (DUAL && k0 >= Ksplit) { Au = (const char*)A2v; Bu = (const char*)B2v; ku = k0 - Ksplit; }

        // ---- stage A tile (TILE m x 32 k) ----
        if (!TRANS_A) {
#pragma unroll
            for (int p = 0; p < TILE / 32; ++p) {
                int idx = tid + p * 256;
                int row = idx >> 3, c4 = idx & 7;
                short4 o;
                if (AU8) {
                    unsigned u = *(const unsigned*)((const unsigned char*)Au +
                                                    (long)(m0 + row) * lda + ku + c4 * 4);
                    o = make_short4(f2bf((float)(u & 255u)), f2bf((float)((u >> 8) & 255u)),
                                    f2bf((float)((u >> 16) & 255u)), f2bf((float)((u >> 24) & 255u)));
                } else {
                    float4 v = *(const float4*)((const float*)Au + (long)(m0 + row) * lda + ku + c4 * 4);
                    if (AFFINE) {
                        int k = ku + c4 * 4;
                        v.x = v.x * scale[k] + shift[k];
                        v.y = v.y * scale[k + 1] + shift[k + 1];
                        v.z = v.z * scale[k + 2] + shift[k + 2];
                        v.w = v.w * scale[k + 3] + shift[k + 3];
                    }
                    o = make_short4(f2bf(v.x), f2bf(v.y), f2bf(v.z), f2bf(v.w));
                }
                *(short4*)&As[row * 40 + c4 * 4] = o;
            }
        } else {
            if (TILE == 128 || tid < 128) {
                int c4 = (TILE == 128) ? (tid & 31) : (tid & 15);
                int g  = (TILE == 128) ? (tid >> 5) : (tid >> 4);
                short* d = &As[(c4 * 4) * 40 + g * 4];
                if (ATRBF16) {
                    const short* src = (const short*)Au + (long)(ku + g * 4) * lda + m0 + c4 * 4;
                    short4 r0 = *(const short4*)(src);
                    short4 r1 = *(const short4*)(src + lda);
                    short4 r2 = *(const short4*)(src + 2 * lda);
                    short4 r3 = *(const short4*)(src + 3 * lda);
                    *(short4*)(d + 0 * 40) = make_short4(r0.x, r1.x, r2.x, r3.x);
                    *(short4*)(d + 1 * 40) = make_short4(r0.y, r1.y, r2.y, r3.y);
                    *(short4*)(d + 2 * 40) = make_short4(r0.z, r1.z, r2.z, r3.z);
                    *(short4*)(d + 3 * 40) = make_short4(r0.w, r1.w, r2.w, r3.w);
                } else {
                    const float* src = (const float*)Au + (long)(ku + g * 4) * lda + m0 + c4 * 4;
                    float4 r0 = *(const float4*)(src);
                    float4 r1 = *(const float4*)(src + lda);
                    float4 r2 = *(const float4*)(src + 2 * lda);
                    float4 r3 = *(const float4*)(src + 3 * lda);
                    *(short4*)(d + 0 * 40) = make_short4(f2bf(r0.x), f2bf(r1.x), f2bf(r2.x), f2bf(r3.x));
                    *(short4*)(d + 1 * 40) = make_short4(f2bf(r0.y), f2bf(r1.y), f2bf(r2.y), f2bf(r3.y));
                    *(short4*)(d + 2 * 40) = make_short4(f2bf(r0.z), f2bf(r1.z), f2bf(r2.z), f2bf(r3.z));
                    *(short4*)(d + 3 * 40) = make_short4(f2bf(r0.w), f2bf(r1.w), f2bf(r2.w), f2bf(r3.w));
                }
            }
        }
        // ---- stage B tile (32 k x TILE n), transposed to Bs[n][k] ----
        if (TILE == 128 || tid < 128) {
            int c4 = (TILE == 128) ? (tid & 31) : (tid & 15);
            int g  = (TILE == 128) ? (tid >> 5) : (tid >> 4);
            short* d = &Bs[(c4 * 4) * 40 + g * 4];
            if (BBF16) {
                const short* src = (const short*)Bu + (long)(ku + g * 4) * ldb + n0 + c4 * 4;
                short4 r0 = *(const short4*)(src);
                short4 r1 = *(const short4*)(src + ldb);
                short4 r2 = *(const short4*)(src + 2 * ldb);
                short4 r3 = *(const short4*)(src + 3 * ldb);
                *(short4*)(d + 0 * 40) = make_short4(r0.x, r1.x, r2.x, r3.x);
                *(short4*)(d + 1 * 40) = make_short4(r0.y, r1.y, r2.y, r3.y);
                *(short4*)(d + 2 * 40) = make_short4(r0.z, r1.z, r2.z, r3.z);
                *(short4*)(d + 3 * 40) = make_short4(r0.w, r1.w, r2.w, r3.w);
            } else {
                const float* src = (const float*)Bu + (long)(ku + g * 4) * ldb + n0 + c4 * 4;
                float4 r0 = *(const float4*)(src);
                float4 r1 = *(const float4*)(src + ldb);
                float4 r2 = *(const float4*)(src + 2 * ldb);
                float4 r3 = *(const float4*)(src + 3 * ldb);
                *(short4*)(d + 0 * 40) = make_short4(f2bf(r0.x), f2bf(r1.x), f2bf(r2.x), f2bf(r3.x));
                *(short4*)(d + 1 * 40) = make_short4(f2bf(r0.y), f2bf(r1.y), f2bf(r2.y), f2bf(r3.y));
                *(short4*)(d + 2 * 40) = make_short4(f2bf(r0.z), f2bf(r1.z), f2bf(r2.z), f2bf(r3.z));
                *(short4*)(d + 3 * 40) = make_short4(f2bf(r0.w), f2bf(r1.w), f2bf(r2.w), f2bf(r3.w));
            }
        }
        __syncthreads();

        s16x8 af[WT], bf[WT];
#pragma unroll
        for (int t = 0; t < WT; ++t) {
            af[t] = *(const s16x8*)&As[(wrow * (TILE / 2) + t * 16 + lane16) * 40 + quad * 8];
            bf[t] = *(const s16x8*)&Bs[(wcol * (TILE / 2) + t * 16 + lane16) * 40 + quad * 8];
        }
#pragma unroll
        for (int i = 0; i < WT; ++i)
#pragma unroll
            for (int j = 0; j < WT; ++j)
                acc[i][j] = __builtin_amdgcn_mfma_f32_16x16x32_bf16(af[i], bf[j], acc[i][j], 0, 0, 0);
        __syncthreads();
    }

#pragma unroll
    for (int i = 0; i < WT; ++i) {
        int gm = m0 + wrow * (TILE / 2) + i * 16 + quad * 4;
#pragma unroll
        for (int j = 0; j < WT; ++j) {
            int gn = n0 + wcol * (TILE / 2) + j * 16 + lane16;
            float bv = bias ? bias[gn] : 0.f;
#pragma unroll
            for (int r = 0; r < 4; ++r) {
                float val = acc[i][j][r] + bv;
                if (RELU) val = fmaxf(val, 0.f);
                if (OBF16) Cs[(long)(gm + r) * ldc + gn] = f2bf(val);
                else       C[(long)(gm + r) * ldc + gn] = val;
            }
        }
    }
}

// ---------------------------------------------------------------------------
// BF16-input MFMA GEMM (no conversion): C = outscale * (A @ B), batched.
// ---------------------------------------------------------------------------
template <bool TRANS_B, bool OBF16>
__global__ __launch_bounds__(256) void bgemm(const short* __restrict__ A,
                                             const short* __restrict__ B,
                                             void* __restrict__ Cv,
                                             float outscale,
                                             int M, int Nc, int K,
                                             int lda, int ldb, int ldc,
                                             long sA, long sB, long sC) {
    __shared__ __align__(16) short As[128 * 40];
    __shared__ __align__(16) short Bs[128 * 40];
    A += (long)blockIdx.z * sA;
    B += (long)blockIdx.z * sB;
    float* C = (float*)Cv + (OBF16 ? 0 : (long)blockIdx.z * sC);
    short* Cs = (short*)Cv + (OBF16 ? (long)blockIdx.z * sC : 0);
    const int m0 = blockIdx.y * 128, n0 = blockIdx.x * 128;
    const int tid = threadIdx.x;
    const int lane16 = tid & 15;
    const int quad = (tid & 63) >> 4;
    const int wrow = (tid >> 6) >> 1, wcol = (tid >> 6) & 1;

    f32x4 acc[4][4] = {};

    for (int k0 = 0; k0 < K; k0 += 32) {
#pragma unroll
        for (int p = 0; p < 2; ++p) {
            int u = tid + p * 256;
            int row = u >> 2, g = u & 3;
            *(s16x8*)&As[row * 40 + g * 8] =
                *(const s16x8*)(A + (long)(m0 + row) * lda + k0 + g * 8);
        }
        if (TRANS_B) {
#pragma unroll
            for (int p = 0; p < 2; ++p) {
                int u = tid + p * 256;
                int row = u >> 2, g = u & 3;
                *(s16x8*)&Bs[row * 40 + g * 8] =
                    *(const s16x8*)(B + (long)(n0 + row) * ldb + k0 + g * 8);
            }
        } else {
            int c4 = tid & 31, g = tid >> 5;
            const short* src = B + (long)(k0 + g * 4) * ldb + n0 + c4 * 4;
            short4 r0 = *(const short4*)(src);
            short4 r1 = *(const short4*)(src + ldb);
            short4 r2 = *(const short4*)(src + 2 * ldb);
            short4 r3 = *(const short4*)(src + 3 * ldb);
            short* d = &Bs[(c4 * 4) * 40 + g * 4];
            *(short4*)(d + 0 * 40) = make_short4(r0.x, r1.x, r2.x, r3.x);
            *(short4*)(d + 1 * 40) = make_short4(r0.y, r1.y, r2.y, r3.y);
            *(short4*)(d + 2 * 40) = make_short4(r0.z, r1.z, r2.z, r3.z);
            *(short4*)(d + 3 * 40) = make_short4(r0.w, r1.w, r2.w, r3.w);
        }
        __syncthreads();

        s16x8 af[4], bf[4];
#pragma unroll
        for (int t = 0; t < 4; ++t) {
            af[t] = *(const s16x8*)&As[(wrow * 64 + t * 16 + lane16) * 40 + quad * 8];
            bf[t] = *(const s16x8*)&Bs[(wcol * 64 + t * 16 + lane16) * 40 + quad * 8];
        }
#pragma unroll
        for (int i = 0; i < 4; ++i)
#pragma unroll
            for (int j = 0; j < 4; ++j)
                acc[i][j] = __builtin_amdgcn_mfma_f32_16x16x32_bf16(af[i], bf[j], acc[i][j], 0, 0, 0);
        __syncthreads();
    }

#pragma unroll
    for (int i = 0; i < 4; ++i) {
        int gm = m0 + wrow * 64 + i * 16 + quad * 4;
#pragma unroll
        for (int j = 0; j < 4; ++j) {
            int gn = n0 + wcol * 64 + j * 16 + lane16;
#pragma unroll
            for (int r = 0; r < 4; ++r) {
                float val = acc[i][j][r] * outscale;
                if (OBF16) Cs[(long)(gm + r) * ldc + gn] = f2bf(val);
                else       C[(long)(gm + r) * ldc + gn] = val;
            }
        }
    }
}

// ---------------------------------------------------------------------------
// qWe[node][d] = (q[node,:] . We[d,:]) / sqrt(H)
// ---------------------------------------------------------------------------
__global__ __launch_bounds__(256) void qwe_kernel(const short* __restrict__ qkvs,
                                                  const float* __restrict__ We,
                                                  float* __restrict__ qWe) {
    __shared__ float sWe[EDIM_ * 128];
    for (int i = threadIdx.x; i < EDIM_ * 128; i += 256) sWe[i] = We[i];
    __syncthreads();
    int i = blockIdx.x * 256 + threadIdx.x;
    int node = i / 5, d = i - node * 5;
    const s16x8* row = (const s16x8*)(qkvs + (long)node * 512);
    float acc = 0.f;
#pragma unroll
    for (int g = 0; g < 16; ++g) {
        s16x8 v = row[g];
#pragma unroll
        for (int j = 0; j < 8; ++j) acc += bf2f(v[j]) * sWe[d * 128 + g * 8 + j];
    }
    qWe[i] = acc * 0.08838834764831845f;
}

// ---------------------------------------------------------------------------
// Fused edge-softmax + P-row build. 16 lanes per dst node, 16 nodes/block.
// ---------------------------------------------------------------------------
__global__ __launch_bounds__(256) void attn_fuse_kernel(const short* __restrict__ S,
                                                        const int* __restrict__ ei,
                                                        const float* __restrict__ eattr,
                                                        const float* __restrict__ qWe,
                                                        const int* __restrict__ rp_dst,
                                                        const int* __restrict__ deg_dst,
                                                        const int* __restrict__ eid_dst,
                                                        short* __restrict__ P,
                                                        float* __restrict__ ea5n) {
    __shared__ float rows[16][512];
    int g = threadIdx.x >> 4;
    int lane = threadIdx.x & 15;
    int node = blockIdx.x * 16 + g;
    float* row = rows[g];
    for (int i = lane; i < 512; i += 16) row[i] = 0.f;
    float qw[EDIM_];
#pragma unroll
    for (int d = 0; d < EDIM_; ++d) qw[d] = qWe[node * EDIM_ + d];
    int start = rp_dst[node], cnt = deg_dst[node];
    const short* Srow = S + (long)node * 512;
    float lsum = 0.f, a5[EDIM_] = {};
    for (int t = lane; t < cnt; t += 16) {
        int e = eid_dst[start + t];
        int src = ei[e] & 511;
        float lg = bf2f(Srow[src]);
        float ea[EDIM_];
#pragma unroll
        for (int d = 0; d < EDIM_; ++d) { ea[d] = eattr[e * EDIM_ + d]; lg += ea[d] * qw[d]; }
        float wv = expf(lg);
        lsum += wv;
#pragma unroll
        for (int d = 0; d < EDIM_; ++d) a5[d] += wv * ea[d];
        atomicAdd(&row[src], wv);
    }
#pragma unroll
    for (int off = 8; off; off >>= 1) {
        lsum += __shfl_xor(lsum, off);
#pragma unroll
        for (int d = 0; d < EDIM_; ++d) a5[d] += __shfl_xor(a5[d], off);
    }
    float inv = (lsum > 0.f) ? 1.f / lsum : 0.f;
    if (lane < EDIM_) {
        float v = lane == 0 ? a5[0] : lane == 1 ? a5[1] : lane == 2 ? a5[2]
                : lane == 3 ? a5[3] : a5[4];
        ea5n[node * EDIM_ + lane] = v * inv;
    }
    unsigned* Pr = (unsigned*)(P + (long)node * 512);
    for (int i = lane; i < 256; i += 16) {
        float v0 = row[2 * i] * inv, v1 = row[2 * i + 1] * inv;
        unsigned pack = (unsigned)(unsigned short)f2bf(v0)
                      | ((unsigned)(unsigned short)f2bf(v1) << 16);
        Pr[i] = pack;
    }
}

// ---------------------------------------------------------------------------
// Dense adjacency count build (uint8 per (src,dst)), by src-CSR.
// ---------------------------------------------------------------------------
__global__ __launch_bounds__(256) void adense_kernel(const int* __restrict__ ei,
                                                     const int* __restrict__ rp_src,
                                                     const int* __restrict__ deg_src,
                                                     const int* __restrict__ eid_src,
                                                     unsigned char* __restrict__ Adense) {
    __shared__ int rows[16][512];
    int g = threadIdx.x >> 4;
    int lane = threadIdx.x & 15;
    int node = blockIdx.x * 16 + g;
    int* row = rows[g];
    for (int i = lane; i < 512; i += 16) row[i] = 0;
    int start = rp_src[node], cnt = deg_src[node];
    for (int t = lane; t < cnt; t += 16) {
        int e = eid_src[start + t];
        int dst = ei[EDGES + e] & 511;
        atomicAdd(&row[dst], 1);
    }
    unsigned* Ar = (unsigned*)(Adense + (long)node * 512);
    for (int i = lane; i < 128; i += 16) {
        unsigned p = (unsigned)row[4 * i]
                   | ((unsigned)row[4 * i + 1] << 8)
                   | ((unsigned)row[4 * i + 2] << 16)
                   | ((unsigned)row[4 * i + 3] << 24);
        Ar[i] = p;
    }
}

// ---------------------------------------------------------------------------
// h = relu(agg + ea5n @ We + skip)
// ---------------------------------------------------------------------------
__global__ __launch_bounds__(256) void hassemble_kernel(float* __restrict__ h,
                                                        const float* __restrict__ ea5n,
                                                        const float* __restrict__ We,
                                                        const short* __restrict__ qkvs) {
    long i = (long)blockIdx.x * 256 + threadIdx.x;
    int node = (int)(i >> 7);
    int c = (int)(i & 127);
    float ecorr = 0.f;
#pragma unroll
    for (int d = 0; d < EDIM_; ++d) ecorr += ea5n[node * EDIM_ + d] * We[d * 128 + c];
    float v = h[i] + ecorr + bf2f(qkvs[(long)node * 512 + 384 + c]);
    h[i] = fmaxf(v, 0.f);
}

// ---------------------------------------------------------------------------
// Row-wise softmax; optionally writes bf16 to a separate buffer
// ---------------------------------------------------------------------------
template <int NC, bool OB>
__global__ __launch_bounds__(256) void softmax_kernel(const float* __restrict__ in,
                                                      void* __restrict__ outv) {
    int wave = threadIdx.x >> 6;
    int lane = threadIdx.x & 63;
    int row = blockIdx.x * 4 + wave;
    const float* p = in + (long)row * NC;
    constexpr int PER = NC / 64;
    float v[PER];
    float mx = -INFINITY;
#pragma unroll
    for (int j = 0; j < PER; ++j) { v[j] = p[lane + j * 64]; mx = fmaxf(mx, v[j]); }
#pragma unroll
    for (int off = 32; off; off >>= 1) mx = fmaxf(mx, __shfl_xor(mx, off));
    float sm = 0.f;
#pragma unroll
    for (int j = 0; j < PER; ++j) { v[j] = expf(v[j] - mx); sm += v[j]; }
#pragma unroll
    for (int off = 32; off; off >>= 1) sm += __shfl_xor(sm, off);
    float inv = 1.f / sm;
    if (OB) {
        short* o = (short*)outv + (long)row * NC;
#pragma unroll
        for (int j = 0; j < PER; ++j) o[lane + j * 64] = f2bf(v[j] * inv);
    } else {
        float* o = (float*)outv + (long)row * NC;
#pragma unroll
        for (int j = 0; j < PER; ++j) o[lane + j * 64] = v[j] * inv;
    }
}

// ---------------------------------------------------------------------------
// Pooled-adj normalization
// ---------------------------------------------------------------------------
template <int KC>
__global__ __launch_bounds__(256) void dinv_kernel(const float* __restrict__ adj,
                                                   float* __restrict__ dinv) {
    int wave = threadIdx.x >> 6;
    int lane = threadIdx.x & 63;
    int row = blockIdx.x * 4 + wave;
    int b = row / KC, r = row % KC;
    const float* p = adj + (long)b * KC * KC + (long)r * KC;
    float s = 0.f;
    for (int j = lane; j < KC; j += 64)
        if (j != r) s += p[j];
#pragma unroll
    for (int off = 32; off; off >>= 1) s += __shfl_xor(s, off);
    if (lane == 0) dinv[row] = 1.f / (sqrtf(s) + 1e-15f);
}

template <int KC>
__global__ __launch_bounds__(256) void scale_adj_kernel(float* __restrict__ adj,
                                                        const float* __restrict__ dinv) {
    long i = (long)blockIdx.x * 256 + threadIdx.x;
    int c = (int)(i % KC);
    long t = i / KC;
    int r = (int)(t % KC);
    int b = (int)(t / KC);
    float v = adj[i];
    v = (r == c) ? 0.f : v * dinv[b * KC + r] * dinv[b * KC + c];
    adj[i] = v;
}

// ---------------------------------------------------------------------------
// Readout
// ---------------------------------------------------------------------------
__global__ __launch_bounds__(128) void readout_kernel(const float* __restrict__ xd3,
                                                      const float* __restrict__ W_lin1,
                                                      const float* __restrict__ b_lin1,
                                                      const float* __restrict__ W_ro,
                                                      const float* __restrict__ b_ro,
                                                      float* __restrict__ out) {
    int b = blockIdx.x, t = threadIdx.x;
    __shared__ float g[128], g2[128], wred[2];
    const float* X = xd3 + (long)b * K2C * 128;
    float s = 0.f;
    for (int r = 0; r < K2C; ++r) s += X[r * 128 + t];
    g[t] = s * (1.f / (float)K2C);
    __syncthreads();
    float u = b_lin1[t];
    for (int k = 0; k < 128; ++k) u += g[k] * W_lin1[k * 128 + t];
    g2[t] = fmaxf(u, 0.f);
    __syncthreads();
    float p = g2[t] * W_ro[t];
#pragma unroll
    for (int off = 32; off; off >>= 1) p += __shfl_xor(p, off);
    if ((t & 63) == 0) wred[t >> 6] = p;
    __syncthreads();
    if (t == 0) {
        float tot = wred[0] + wred[1] + b_ro[0];
        out[b] = 1.f / (1.f + expf(-tot));
    }
}

// ---------------------------------------------------------------------------
extern "C" void kernel_launch(void* const* d_in, const int* in_sizes, int n_in,
                              void* d_out, int out_size, void* d_ws, size_t ws_size,
                              hipStream_t stream) {
    const float* x      = (const float*)d_in[0];
    const int*   ei     = (const int*)d_in[1];
    const float* eattr  = (const float*)d_in[2];
    const float* gamma  = (const float*)d_in[4];
    const float* beta   = (const float*)d_in[5];
    const float* Wq     = (const float*)d_in[6];
    const float* bq     = (const float*)d_in[7];
    const float* Wk     = (const float*)d_in[8];
    const float* bk     = (const float*)d_in[9];
    const float* Wv     = (const float*)d_in[10];
    const float* bv     = (const float*)d_in[11];
    const float* We     = (const float*)d_in[12];
    const float* Wskip  = (const float*)d_in[13];
    const float* bskip  = (const float*)d_in[14];
    const float* W_mlp1 = (const float*)d_in[15];
    const float* b_mlp1 = (const float*)d_in[16];
    const float* W2_rel = (const float*)d_in[17];
    const float* b2_rel = (const float*)d_in[18];
    const float* W2_root= (const float*)d_in[19];
    const float* W_mlp2 = (const float*)d_in[20];
    const float* b_mlp2 = (const float*)d_in[21];
    const float* W3_rel = (const float*)d_in[22];
    const float* b3_rel = (const float*)d_in[23];
    const float* W3_root= (const float*)d_in[24];
    const float* W_lin1 = (const float*)d_in[25];
    const float* b_lin1 = (const float*)d_in[26];
    const float* W_ro   = (const float*)d_in[27];
    const float* b_ro   = (const float*)d_in[28];
    float* out = (float*)d_out;

    char* w = (char*)d_ws;
    const size_t MB = 1ull << 20;
    // Workspace plan (peak 110 MB), lifetime-aliased:
    //  [0,32)   qkvs bf16 (4-8) → s1f fp32 (9) → adj2/xp2/t3/xd3 (15+)
    //  [32,64)  S bf16 (6-7) → h fp32 [32,48) (8-11) ; T1s bf16 [48,64) (10-11)
    //           → tgc2[48,56) xd2[56,64) (13+)
    //  [64,96)  P bf16 (7-8) → s1b bf16 [64,80) (9-11) + Adense u8 [80,96) (8-10)
    //           → s2[64,72) t2[72,80) (14+) + adj1 [80,96) (11-15)
    //  [96,104) qWe/ea5n (5-8) → xp1 (11-13)
    //  [104,110) misc
    short* qkvs = (short*)(w + 0);          // [NTOT,512] bf16 32MB
    float* s1f  = (float*)(w + 0);          // [NTOT,256] fp32 32MB (pre-softmax)
    short* S    = (short*)(w + 32 * MB);    // [NTOT,512] bf16 32MB
    float* h    = (float*)(w + 32 * MB);    // [NTOT,128] 16MB (over dead S)
    short* T1s  = (short*)(w + 48 * MB);    // [NTOT,256] bf16 16MB
    short* P    = (short*)(w + 64 * MB);    // [NTOT,512] bf16 32MB
    short* s1b  = (short*)(w + 64 * MB);    // [NTOT,256] bf16 16MB (over dead P lo)
    unsigned char* Aden = (unsigned char*)(w + 80 * MB);  // [NTOT,512] u8 16MB (over dead P hi)
    float* tgc2 = (float*)(w + 48 * MB);    // [B,256,128] 8MB
    float* xd2  = (float*)(w + 56 * MB);    // [B,256,128] 8MB
    float* s2   = (float*)(w + 64 * MB);    // [B,256,128] 8MB
    float* t2   = (float*)(w + 72 * MB);    // [B,256,128] 8MB
    float* adj2 = (float*)(w + 0);          // [B,128,128] 4MB
    float* xp2  = (float*)(w + 4 * MB);     // [B,128,128] 4MB
    float* t3   = (float*)(w + 8 * MB);     // [B,128,128] 4MB
    float* xd3  = (float*)(w + 12 * MB);    // [B,128,128] 4MB
    float* adj1 = (float*)(w + 80 * MB);    // [B,256,256] 16MB (over dead Adense)
    float* xp1  = (float*)(w + 96 * MB);    // [B,256,128] 8MB
    float* qWe  = (float*)(w + 96 * MB);    // [NTOT,5] 640KB (dead before xp1)
    float* ea5n = (float*)(w + 97 * MB);    // [NTOT,5] 640KB
    char* misc  = w + 104 * MB;
    float* W4     = (float*)(misc + 0x00000);
    float* bias4  = (float*)(misc + 0x40000);
    float* scale  = (float*)(misc + 0x41400);
    float* shift  = (float*)(misc + 0x41600);
    float* dinv1  = (float*)(misc + 0x42000);
    float* dinv2  = (float*)(misc + 0x52000);
    int* deg_src  = (int*)(misc + 0x60000);
    int* deg_dst  = (int*)(misc + 0x80000);
    int* rp_src   = (int*)(misc + 0xA0000);
    int* rp_dst   = (int*)(misc + 0xC0000);
    int* cur_src  = (int*)(misc + 0xE0000);
    int* cur_dst  = (int*)(misc + 0x100000);
    int* eid_src  = (int*)(misc + 0x120000);
    int* eid_dst  = (int*)(misc + 0x320000);
    float* psum   = (float*)(misc + 0x520000);
    float* psq    = (float*)(misc + 0x540000);

    hipMemsetAsync(deg_src, 0, 2 * NTOT * sizeof(int), stream);

    // 1. BatchNorm affine params
    bn_stats_kernel<<<256, 256, 0, stream>>>(x, psum, psq);
    bn_finalize_kernel<<<1, 128, 0, stream>>>(psum, psq, gamma, beta, scale, shift);

    // 2. Pack fused qkvs weights
    pack_w4_kernel<<<256, 256, 0, stream>>>(Wq, Wk, Wv, Wskip, bq, bk, bv, bskip, W4, bias4);

    // 3. CSR by src and dst
    hist_kernel<<<EDGES / 256, 256, 0, stream>>>(ei, deg_src, deg_dst);
    scan2_kernel<<<2, 1024, 0, stream>>>(deg_src, rp_src, cur_src, deg_dst, rp_dst, cur_dst);
    scatter_kernel<<<EDGES / 256, 256, 0, stream>>>(ei, cur_src, cur_dst, eid_src, eid_dst);

    // 4. qkvs(bf16) = BN(x) @ [Wq|Wk|Wv|Wskip] + biases
    mgemm<128, false, true, false, false, true, false, false, false>
        <<<dim3(4, 256, 1), 256, 0, stream>>>(
        x, W4, nullptr, nullptr, 0, bias4, qkvs, scale, shift,
        NTOT, 512, 128, 128, 512, 512, 0, 0, 0);

    // 5. qWe = q @ We^T / sqrt(H)
    qwe_kernel<<<(NTOT * EDIM_) / 256, 256, 0, stream>>>(qkvs, We, qWe);

    // 6. S(bf16) = (Q @ K^T) / sqrt(H) per graph
    bgemm<true, true><<<dim3(4, 4, BGRAPH), 256, 0, stream>>>(
        qkvs + 0, qkvs + 128, S, 0.08838834764831845f,
        NNODE, NNODE, 128, 512, 512, 512,
        (long)NNODE * 512, (long)NNODE * 512, (long)NNODE * NNODE);

    // 7. Fused edge-softmax + normalized-P build
    attn_fuse_kernel<<<NTOT / 16, 256, 0, stream>>>(
        S, ei, eattr, qWe, rp_dst, deg_dst, eid_dst, P, ea5n);

    // 8. agg = P @ V ; build Adense (upper dead-P region) ; assemble h
    bgemm<false, false><<<dim3(1, 4, BGRAPH), 256, 0, stream>>>(
        P, qkvs + 256, h, 1.0f,
        NNODE, 128, NNODE, 512, 512, 128,
        (long)NNODE * 512, (long)NNODE * 512, (long)NNODE * 128);
    adense_kernel<<<NTOT / 16, 256, 0, stream>>>(ei, rp_src, deg_src, eid_src, Aden);
    hassemble_kernel<<<(NTOT * 128) / 256, 256, 0, stream>>>(h, ea5n, We, qkvs);

    // 9. s1f = h @ W_mlp1 + b ; s1b(bf16) = softmax(s1f)
    mgemm<128, false, false, false, false, false, false, false, false>
        <<<dim3(2, 256, 1), 256, 0, stream>>>(
        h, W_mlp1, nullptr, nullptr, 0, b_mlp1, s1f, nullptr, nullptr,
        NTOT, K1C, 128, 128, K1C, K1C, 0, 0, 0);
    softmax_kernel<K1C, true><<<NTOT / 4, 256, 0, stream>>>(s1f, s1b);

    // 10. T1(bf16) = Adense(u8) @ s1b(bf16) per graph
    mgemm<128, false, false, false, false, true, true, true, false>
        <<<dim3(2, 4, BGRAPH), 256, 0, stream>>>(
        Aden, s1b, nullptr, nullptr, 0, nullptr, T1s, nullptr, nullptr,
        NNODE, K1C, NNODE, NNODE, K1C, K1C,
        (long)NNODE * NNODE, (long)NNODE * K1C, (long)NNODE * K1C);

    // 11. adj1 = s1b^T T1s (all-bf16) ; xp1 = s1b^T h (64-tile)
    mgemm<128, true, false, false, false, false, false, true, true>
        <<<dim3(2, 2, BGRAPH), 256, 0, stream>>>(
        s1b, T1s, nullptr, nullptr, 0, nullptr, adj1, nullptr, nullptr,
        K1C, K1C, NNODE, K1C, K1C, K1C,
        (long)NNODE * K1C, (long)NNODE * K1C, (long)K1C * K1C);
    mgemm<64, true, false, false, false, false, false, false, true>
        <<<dim3(2, 4, BGRAPH), 256, 0, stream>>>(
        s1b, h, nullptr, nullptr, 0, nullptr, xp1, nullptr, nullptr,
        K1C, 128, NNODE, K1C, 128, 128,
        (long)NNODE * K1C, (long)NNODE * 128, (long)K1C * 128);

    // 12. Normalize adj1
    dinv_kernel<K1C><<<(BGRAPH * K1C) / 4, 256, 0, stream>>>(adj1, dinv1);
    scale_adj_kernel<K1C><<<(BGRAPH * K1C * K1C) / 256, 256, 0, stream>>>(adj1, dinv1);

    // 13. GraphConv2 (64-tile)
    mgemm<64, false, false, false, false, false, false, false, false>
        <<<dim3(2, 4, BGRAPH), 256, 0, stream>>>(
        adj1, xp1, nullptr, nullptr, 0, nullptr, tgc2, nullptr, nullptr,
        K1C, 128, K1C, K1C, 128, 128,
        (long)K1C * K1C, (long)K1C * 128, (long)K1C * 128);
    mgemm<64, false, false, true, true, false, false, false, false>
        <<<dim3(2, 256, 1), 256, 0, stream>>>(
        tgc2, W2_rel, xp1, W2_root, 128, b2_rel, xd2, nullptr, nullptr,
        BGRAPH * K1C, 128, 256, 128, 128, 128, 0, 0, 0);

    // 14. s2 = softmax(xd2 @ W_mlp2 + b_mlp2) (64-tile)
    mgemm<64, false, false, false, false, false, false, false, false>
        <<<dim3(2, 256, 1), 256, 0, stream>>>(
        xd2, W_mlp2, nullptr, nullptr, 0, b_mlp2, s2, nullptr, nullptr,
        BGRAPH * K1C, K2C, 128, 128, K2C, K2C, 0, 0, 0);
    softmax_kernel<K2C, false><<<(BGRAPH * K1C) / 4, 256, 0, stream>>>(s2, s2);

    // 15. Pool2 (64-tile)
    mgemm<64, false, false, false, false, false, false, false, false>
        <<<dim3(2, 4, BGRAPH), 256, 0, stream>>>(
        adj1, s2, nullptr, nullptr, 0, nullptr, t2, nullptr, nullptr,
        K1C, K2C, K1C, K1C, K2C, K2C,
        (long)K1C * K1C, (long)K1C * K2C, (long)K1C * K2C);
    mgemm<64, true, false, false, false, false, false, false, false>
        <<<dim3(2, 2, BGRAPH), 256, 0, stream>>>(
        s2, t2, nullptr, nullptr, 0, nullptr, adj2, nullptr, nullptr,
        K2C, K2C, K1C, K2C, K2C, K2C,
        (long)K1C * K2C, (long)K1C * K2C, (long)K2C * K2C);
    mgemm<64, true, false, false, false, false, false, false, false>
        <<<dim3(2, 2, BGRAPH), 256, 0, stream>>>(
        s2, xd2, nullptr, nullptr, 0, nullptr, xp2, nullptr, nullptr,
        K2C, 128, K1C, K2C, 128, 128,
        (long)K1C * K2C, (long)K1C * 128, (long)K2C * 128);

    // 16. Normalize adj2
    dinv_kernel<K2C><<<(BGRAPH * K2C) / 4, 256, 0, stream>>>(adj2, dinv2);
    scale_adj_kernel<K2C><<<(BGRAPH * K2C * K2C) / 256, 256, 0, stream>>>(adj2, dinv2);

    // 17. GraphConv3 (64-tile)
    mgemm<64, false, false, false, false, false, false, false, false>
        <<<dim3(2, 2, BGRAPH), 256, 0, stream>>>(
        adj2, xp2, nullptr, nullptr, 0, nullptr, t3, nullptr, nullptr,
        K2C, 128, K2C, K2C, 128, 128,
        (long)K2C * K2C, (long)K2C * 128, (long)K2C * 128);
    mgemm<64, false, false, false, true, false, false, false, false>
        <<<dim3(2, 128, 1), 256, 0, stream>>>(
        t3, W3_rel, xp2, W3_root, 128, b3_rel, xd3, nullptr, nullptr,
        BGRAPH * K2C, 128, 256, 128, 128, 128, 0, 0, 0);

    // 18. Readout
    readout_kernel<<<BGRAPH, 128, 0, stream>>>(xd3, W_lin1, b_lin1, W_ro, b_ro, out);

    (void)in_sizes; (void)n_in; (void)out_size; (void)ws_size;
}